// Round 3
// baseline (1113.555 us; speedup 1.0000x reference)
//
#include <hip/hip_runtime.h>

#define NB 2048
#define HDM 64
#define NLAY 5
#define NBLK 512

typedef __bf16 bf16x8 __attribute__((ext_vector_type(8)));
typedef float v4f __attribute__((ext_vector_type(4)));

__device__ __forceinline__ float sigmoidf_(float x){ return 1.f/(1.f+__expf(-x)); }
__device__ __forceinline__ float tanhfast_(float x){
  x = fminf(fmaxf(x, -15.f), 15.f);
  float e = __expf(2.f*x);
  return (e-1.f)/(e+1.f);
}
__device__ __forceinline__ unsigned short f2b_rne(float f){
  unsigned u = __float_as_uint(f);
  unsigned r = u + 0x7FFFu + ((u>>16)&1u);
  return (unsigned short)(r>>16);
}
__device__ __forceinline__ unsigned pk2(float a, float b){
  unsigned ua = (__float_as_uint(a) + 0x8000u) >> 16;
  unsigned ub = (__float_as_uint(b) + 0x8000u) & 0xFFFF0000u;
  return ua | ub;
}

// ============================ fused kernel (plain launch, software grid barrier) ============
// 512 blocks x 256 threads, __launch_bounds__(256,2): LDS 18.9KB*2 = 37.9KB <= 160KB and
// VGPR 120 <= 128 -> exactly 2 blocks/CU * 256 CU = 512 resident blocks. Plain launch
// (graph-capture safe, proven in round 2); watchdog in gsync makes any residency surprise
// a loud numerical failure instead of a hang.

struct KArgs {
  const float *x, *tt, *freqs, *fc1W, *fc1b, *fc2W, *fc2b, *nodeW, *nodeb,
              *tprojW, *tprojb, *tcatW, *tcatb, *penb, *pelW, *pelb, *catW, *catb,
              *convWg, *gruWih, *grubih, *gruWhh, *grubhh, *Wqkv, *bqkv, *Wo, *bo,
              *bng, *bnb, *W1, *b1, *W2, *b2, *outW, *outb;
  float *htime, *hbuf, *gh, *s1, *s2, *smlp, *o_out, *hsum, *bnacc, *h0p, *out;
  unsigned short *Qb, *Kb, *Vt;
  unsigned *bar;
};

union SMem {
  struct { float xs[16*260]; float tb0[256]; float tb1[256]; } pre;             // 18688 B
  struct { float sa[256]; float sb[256]; float cvec[64]; } as;                  // 2304 B
  struct { float sa[256]; } a;                                                  // 1024 B
  struct { unsigned short Pl[4*640]; float Os[4*272]; float ms[64]; float ls[64]; } at; // 9984 B
  struct { float sa[256]; float os[256]; float smv[64]; float sgi[192]; float Sb1[256]; float Sb2[256]; } b2; // 5120 B
  struct { float sa[256]; float sh[4*128]; float S2[256]; } c;                  // 4096 B
  struct { float hsT[64*20]; } o;                                               // 5120 B
};

// Slot-per-barrier grid sync (slots zeroed each launch by the in-graph memset).
// KEY FIX vs round 2: poll with RELAXED atomic loads (coherent sc1 read, NO cache
// maintenance). Round 2 polled with ACQUIRE -> one L2 invalidate PER POLL ITERATION,
// which thrashed the XCD's L2 under the still-working straggler blocks (~42us/barrier).
// Here: exactly one release fence (waitcnt+L2 writeback) before the arrive-add and one
// acquire fence (invalidate) after the spin completes.
__device__ __forceinline__ void gsync(unsigned* slotp){
  __syncthreads();   // hipcc drains vmcnt/lgkmcnt before s_barrier -> all block stores done
  if (threadIdx.x == 0){
    __builtin_amdgcn_fence(__ATOMIC_RELEASE, "agent");   // single L2 writeback
    __hip_atomic_fetch_add(slotp, 1u, __ATOMIC_RELAXED, __HIP_MEMORY_SCOPE_AGENT);
    unsigned spins = 0u;
    while (__hip_atomic_load(slotp, __ATOMIC_RELAXED, __HIP_MEMORY_SCOPE_AGENT) < (unsigned)NBLK){
      __builtin_amdgcn_s_sleep(4);
      if (++spins > 500000u) break;    // fail loud (wrong data), never hang the container
    }
    __builtin_amdgcn_fence(__ATOMIC_ACQUIRE, "agent");   // single cache invalidate
  }
  __syncthreads();
}

__global__ __launch_bounds__(256, 2) void k_fused(KArgs A)
{
  __shared__ SMem sm;
  const int t = threadIdx.x;
  const int b = blockIdx.x;
  int slot = 0;

  // ================= Phase P: zero accumulators + time-embedding + GEMM1 =================
  if (b == 0){
    for (int i = t; i < 320 + 1920; i += 256) A.hsum[i] = 0.f;   // hsum + bnacc contiguous
  }
  {
    // time embedding for rows b*4 + r (all 4 row groups active)
    const int r = t>>6, c = t&63;
    const int row = b*4 + r;
    const float tv = A.tt[row];
    float te[16];
    #pragma unroll
    for (int j=0;j<8;++j){
      float sv, cv;
      __sincosf(6.28318530717958647692f*tv*A.freqs[j], &sv, &cv);
      te[j]=sv; te[j+8]=cv;
    }
    float a = A.fc1b[c];
    #pragma unroll
    for (int j=0;j<16;++j) a += te[j]*A.fc1W[j*64+c];
    sm.pre.tb0[r*64+c] = a*sigmoidf_(a);
    __syncthreads();
    float b2v = A.fc2b[c];
    #pragma unroll 8
    for (int k=0;k<64;++k) b2v += sm.pre.tb0[r*64+k]*A.fc2W[k*64+c];
    sm.pre.tb1[r*64+c] = b2v;
    __syncthreads();
    float hti = A.tprojb[c];
    #pragma unroll 8
    for (int k=0;k<64;++k) hti += sm.pre.tb1[r*64+k]*A.tprojW[k*64+c];
    A.htime[row*64+c] = hti;
  }
  {
    // GEMM1 partial: rowgroup rg = b>>2 (16 rows), K-quarter kq = b&3 (1024 k), 4 chunks of 256
    const int rg = b>>2, kq = b&3;
    const int rows0 = rg*16, k0 = kq*1024;
    const int col4 = (t&15)*4;
    const int rq4  = ((t>>4)&3)*4;
    const int ksub = (t>>6)*64;

    float4 a0={0,0,0,0}, a1={0,0,0,0}, a2={0,0,0,0}, a3={0,0,0,0};

    for (int ch=0; ch<4; ++ch){
      __syncthreads();
      #pragma unroll
      for (int i=0;i<4;++i){
        int fi = t + 256*i;
        int xr = fi>>6, kk = (fi&63)<<2;
        *(float4*)&sm.pre.xs[xr*260+kk] =
            *(const float4*)&A.x[(size_t)(rows0+xr)*4096 + k0 + ch*256 + kk];
      }
      __syncthreads();
      const float* wp = &A.nodeW[(size_t)(k0 + ch*256 + ksub)*64 + col4];
      const float* xp = &sm.pre.xs[rq4*260 + ksub];
      #pragma unroll 8
      for (int kk=0; kk<64; ++kk){
        float4 w  = *(const float4*)&wp[kk*64];
        float x0 = xp[kk];
        float x1 = xp[260+kk];
        float x2 = xp[520+kk];
        float x3 = xp[780+kk];
        a0.x += x0*w.x; a0.y += x0*w.y; a0.z += x0*w.z; a0.w += x0*w.w;
        a1.x += x1*w.x; a1.y += x1*w.y; a1.z += x1*w.z; a1.w += x1*w.w;
        a2.x += x2*w.x; a2.y += x2*w.y; a2.z += x2*w.z; a2.w += x2*w.w;
        a3.x += x3*w.x; a3.y += x3*w.y; a3.z += x3*w.z; a3.w += x3*w.w;
      }
    }
    __syncthreads();
    {
      const int kqi = t>>6;
      *(float4*)&sm.pre.xs[(kqi*16 + rq4 + 0)*64 + col4] = a0;
      *(float4*)&sm.pre.xs[(kqi*16 + rq4 + 1)*64 + col4] = a1;
      *(float4*)&sm.pre.xs[(kqi*16 + rq4 + 2)*64 + col4] = a2;
      *(float4*)&sm.pre.xs[(kqi*16 + rq4 + 3)*64 + col4] = a3;
    }
    __syncthreads();
    {
      const int row = t>>4, c4 = (t&15)*4;
      float4 s = {0,0,0,0};
      #pragma unroll
      for (int q=0;q<4;++q){
        float4 v = *(const float4*)&sm.pre.xs[(q*16+row)*64 + c4];
        s.x+=v.x; s.y+=v.y; s.z+=v.z; s.w+=v.w;
      }
      *(float4*)&A.h0p[(size_t)kq*(NB*HDM) + (rows0+row)*64 + c4] = s;
    }
  }
  gsync(A.bar + (slot++));   // all GEMM1 partials + zeroing visible

  // ================= Phase assemble: rows b*4 + r =================
  {
    const int r = t>>6, c = t&63;
    const int row = b*4 + r;
    if (r==0){
      float pl[16];
      #pragma unroll
      for (int j=0;j<16;++j){
        float a = A.pelb[j];
        for (int w=0;w<20;++w) a += A.penb[w]*A.pelW[w*16+j];
        pl[j]=a;
      }
      float a = A.catb[c];
      #pragma unroll
      for (int j=0;j<16;++j) a += pl[j]*A.catW[(64+j)*64+c];
      sm.as.cvec[c]=a;
    }
    float h0 = A.nodeb[c];
    #pragma unroll
    for (int q=0;q<4;++q) h0 += A.h0p[(size_t)q*(NB*HDM) + row*64 + c];
    sm.as.sa[t] = h0;
    sm.as.sb[t] = A.htime[row*64+c];
    __syncthreads();
    float a = A.tcatb[c];
    #pragma unroll 4
    for (int k=0;k<64;++k){
      a += sm.as.sa[r*64+k]*A.tcatW[k*64+c];
      a += sm.as.sb[r*64+k]*A.tcatW[(64+k)*64+c];
    }
    __syncthreads();
    sm.as.sa[t] = a;
    __syncthreads();
    float hv = sm.as.cvec[c];
    #pragma unroll 8
    for (int k=0;k<64;++k) hv += sm.as.sa[r*64+k]*A.catW[k*64+c];
    A.hbuf[row*64+c] = hv;
  }
  // no grid sync needed: layer-0 phase A reads only this block's own 4 rows of hbuf

  // ================= layers =================
  for (int l=0; l<NLAY; ++l){
    const float* bnaccPrev = (l==0) ? A.bnacc : A.bnacc + (l-1)*384;
    const float* gPrev = (l==0) ? A.bng : A.bng + (l-1)*192 + 128;
    const float* bPrev = (l==0) ? A.bnb : A.bnb + (l-1)*192 + 128;
    const float* Whh = A.gruWhh + l*12288;
    const float* bhh = A.grubhh + l*192;
    const float* Wq  = A.Wqkv + l*12288;
    const float* bqv = A.bqkv + l*192;
    float* hsumL  = A.hsum + l*64;
    float* bnaccL = A.bnacc + l*384;

    // ---- Phase A: [bn3 prev] + hsum + gh + bf16 QKV packs (4 rows) ----
    __syncthreads();   // protect LDS union reuse vs preceding phase
    {
      const int row0 = b*4;
      const int rl = t>>6, c = t&63;
      const int row = row0 + rl;
      float hv;
      if (l==0){
        hv = A.hbuf[row*64+c];
      } else {
        float mu = bnaccPrev[256+c]*(1.f/NB);
        float va = bnaccPrev[320+c]*(1.f/NB) - mu*mu;
        hv = gPrev[c]*(A.smlp[row*64+c]-mu)*rsqrtf(va+1e-5f)+bPrev[c];
        A.hbuf[row*64+c] = hv;
      }
      sm.a.sa[t] = hv;
      __syncthreads();
      if (t<64){
        float s = sm.a.sa[t]+sm.a.sa[64+t]+sm.a.sa[128+t]+sm.a.sa[192+t];
        atomicAdd(&hsumL[t], s);
      }
      if (t < 192){
        const int cc = t;
        float ag[4], aq[4];
        float bh = bhh[cc], bq_ = bqv[cc];
        #pragma unroll
        for (int rl2=0;rl2<4;++rl2){ ag[rl2]=bh; aq[rl2]=bq_; }
        #pragma unroll 4
        for (int k=0;k<64;++k){
          float wh = Whh[k*192+cc];
          float wq = Wq [k*192+cc];
          #pragma unroll
          for (int rl2=0;rl2<4;++rl2){
            float hk = sm.a.sa[rl2*64+k];
            ag[rl2] += hk*wh;
            aq[rl2] += hk*wq;
          }
        }
        #pragma unroll
        for (int rl2=0;rl2<4;++rl2){
          int rw = row0 + rl2;
          A.gh[(size_t)rw*192+cc] = ag[rl2];
          float aqv = aq[rl2];
          if (cc < 64){
            int hd = cc>>4, dh = cc&15;
            size_t base = ((size_t)(hd<<11) + rw)*32;
            A.Qb[base+dh] = f2b_rne(aqv*0.25f);
            A.Qb[base+16+dh] = 0;
          } else if (cc < 128){
            int c2 = cc-64, hd = c2>>4, dh = c2&15;
            size_t base = ((size_t)(hd<<11) + rw)*32;
            A.Kb[base+dh] = f2b_rne(aqv);
            A.Kb[base+16+dh] = 0;
          } else {
            int c2 = cc-128, hd = c2>>4, dh = c2&15;
            A.Vt[((size_t)(hd*16+dh))*2048 + rw] = f2b_rne(aqv);
          }
        }
      }
    }
    gsync(A.bar + (slot++));   // QKV complete

    // ---- Phase attn: unit b = (qt = b&127, head = b>>7), 4 waves x 512 keys ----
    {
      const int w = t>>6, lane = t&63;
      const int q15 = lane & 15, quad = lane >> 4;
      const int qt = b & 127, head = b>>7;
      const int qrow = qt*16 + q15;
      const int key00 = w*512;
      unsigned short* Plw = &sm.at.Pl[w*640];

      const bf16x8 qf = *(const bf16x8*)&A.Qb[(((size_t)(head<<11))+qrow)*32 + quad*8];
      const unsigned short* Kb_h = A.Kb + ((size_t)(head<<11))*32;
      const unsigned short* Vrow = A.Vt + ((size_t)(head*16+q15))*2048;

      v4f O = {0.f,0.f,0.f,0.f};
      float m = -1e30f, lsum = 0.f;

      bf16x8 kf0 = *(const bf16x8*)&Kb_h[(size_t)(key00 + q15)*32 + quad*8];
      bf16x8 kf1 = *(const bf16x8*)&Kb_h[(size_t)(key00 + 16 + q15)*32 + quad*8];
      bf16x8 vf  = *(const bf16x8*)&Vrow[key00 + quad*8];

      for (int c=0; c<16; ++c){
        bf16x8 nk0, nk1, nv;
        if (c < 15){
          int nk = key00 + (c+1)*32;
          nk0 = *(const bf16x8*)&Kb_h[(size_t)(nk + q15)*32 + quad*8];
          nk1 = *(const bf16x8*)&Kb_h[(size_t)(nk + 16 + q15)*32 + quad*8];
          nv  = *(const bf16x8*)&Vrow[nk + quad*8];
        }
        v4f z = {0.f,0.f,0.f,0.f};
        v4f s0 = __builtin_amdgcn_mfma_f32_16x16x32_bf16(kf0, qf, z, 0,0,0);
        v4f s1 = __builtin_amdgcn_mfma_f32_16x16x32_bf16(kf1, qf, z, 0,0,0);
        float cmax = fmaxf(fmaxf(fmaxf(s0[0],s0[1]),fmaxf(s0[2],s0[3])),
                           fmaxf(fmaxf(s1[0],s1[1]),fmaxf(s1[2],s1[3])));
        cmax = fmaxf(cmax, __shfl_xor(cmax,16,64));
        cmax = fmaxf(cmax, __shfl_xor(cmax,32,64));
        float mnew = fmaxf(m, cmax);
        float alpha = __expf(m - mnew);
        float p0=__expf(s0[0]-mnew), p1=__expf(s0[1]-mnew), p2=__expf(s0[2]-mnew), p3=__expf(s0[3]-mnew);
        float p4=__expf(s1[0]-mnew), p5=__expf(s1[1]-mnew), p6=__expf(s1[2]-mnew), p7=__expf(s1[3]-mnew);
        lsum = alpha*lsum + ((p0+p1)+(p2+p3)+((p4+p5)+(p6+p7)));
        m = mnew;
        O[0]*=alpha; O[1]*=alpha; O[2]*=alpha; O[3]*=alpha;
        *(uint2*)&Plw[q15*40 + quad*4]      = make_uint2(pk2(p0,p1), pk2(p2,p3));
        *(uint2*)&Plw[q15*40 + 16 + quad*4] = make_uint2(pk2(p4,p5), pk2(p6,p7));
        asm volatile("s_waitcnt lgkmcnt(0)" ::: "memory");
        bf16x8 pf = *(const bf16x8*)&Plw[q15*40 + quad*8];
        O = __builtin_amdgcn_mfma_f32_16x16x32_bf16(vf, pf, O, 0,0,0);
        kf0 = nk0; kf1 = nk1; vf = nv;
      }
      lsum += __shfl_xor(lsum,16,64);
      lsum += __shfl_xor(lsum,32,64);
      #pragma unroll
      for (int j=0;j<4;++j) sm.at.Os[w*272 + q15*17 + quad*4 + j] = O[j];
      if (quad==0){ sm.at.ms[w*16+q15]=m; sm.at.ls[w*16+q15]=lsum; }
      __syncthreads();
      {
        const int dh = t&15, q = t>>4;
        float m0=sm.at.ms[q], m1=sm.at.ms[16+q], m2=sm.at.ms[32+q], m3=sm.at.ms[48+q];
        float mm = fmaxf(fmaxf(m0,m1),fmaxf(m2,m3));
        float a0=__expf(m0-mm), a1=__expf(m1-mm), a2=__expf(m2-mm), a3=__expf(m3-mm);
        float ll = a0*sm.at.ls[q]+a1*sm.at.ls[16+q]+a2*sm.at.ls[32+q]+a3*sm.at.ls[48+q];
        float oo = a0*sm.at.Os[q*17+dh] + a1*sm.at.Os[272+q*17+dh]
                 + a2*sm.at.Os[544+q*17+dh] + a3*sm.at.Os[816+q*17+dh];
        A.o_out[(size_t)(qt*16+q)*64 + head*16 + dh] = oo / ll;
      }
    }
    gsync(A.bar + (slot++));   // o_out complete

    // ---- Phase B2: o-proj + GRU + bn1/bn2 stats (4 rows) ----
    {
      const float* Wg  = A.convWg + l*4096;
      const float* Wih = A.gruWih + l*12288;
      const float* bih = A.grubih + l*192;
      const float* WoL = A.Wo + l*4096;
      const float* boL = A.bo + l*64;
      const int row0 = b*4;

      if (t<64){
        float a=0.f;
        #pragma unroll 8
        for (int k=0;k<64;++k) a += hsumL[k]*Wg[k*64+t];
        sm.b2.smv[t]=a;
      }
      {
        const int rl = t>>6, c = t&63;
        sm.b2.sa[t] = A.hbuf[(size_t)(row0+rl)*64+c];
        sm.b2.os[t] = A.o_out[(size_t)(row0+rl)*64+c];
      }
      __syncthreads();
      if (t<192){
        float a = bih[t];
        #pragma unroll 8
        for (int k=0;k<64;++k) a += sm.b2.smv[k]*Wih[k*192+t];
        sm.b2.sgi[t]=a;
      }
      __syncthreads();

      {
        const int c = t&63, rg = t>>6;   // one row per thread
        float o2 = boL[c];
        #pragma unroll 4
        for (int k=0;k<64;++k) o2 += sm.b2.os[rg*64+k]*WoL[k*64+c];
        const int row = row0 + rg;
        float hv = sm.b2.sa[rg*64+c];
        float s2v = o2 + hv;
        float ir = sm.b2.sgi[c]      + A.gh[(size_t)row*192+c];
        float iz = sm.b2.sgi[64+c]   + A.gh[(size_t)row*192+64+c];
        float inn = sm.b2.sgi[128+c];
        float hn  = A.gh[(size_t)row*192+128+c];
        float rr_ = sigmoidf_(ir);
        float zz  = sigmoidf_(iz);
        float nn  = tanhfast_(inn + rr_*hn);
        float s1v = (1.f-zz)*nn + zz*hv + hv;   // hc + h
        A.s1[(size_t)row*64+c] = s1v;
        A.s2[(size_t)row*64+c] = s2v;
        sm.b2.Sb1[rg*64+c] = s1v;
        sm.b2.Sb2[rg*64+c] = s2v;
      }
      __syncthreads();
      if (t<64){
        float a=0.f,aq=0.f,bb=0.f,bq2=0.f;
        #pragma unroll
        for (int rl=0;rl<4;++rl){
          float v1 = sm.b2.Sb1[rl*64+t], v2 = sm.b2.Sb2[rl*64+t];
          a+=v1; aq+=v1*v1; bb+=v2; bq2+=v2*v2;
        }
        atomicAdd(&bnaccL[t],a);     atomicAdd(&bnaccL[64+t],aq);
        atomicAdd(&bnaccL[128+t],bb); atomicAdd(&bnaccL[192+t],bq2);
      }
    }
    gsync(A.bar + (slot++));   // bn1/bn2 stats complete

    // ---- Phase C: bn1/bn2 apply + MLP + bn3 stats (4 rows) ----
    {
      const float* bngL = A.bng + l*192;
      const float* bnbL = A.bnb + l*192;
      const float* W1l = A.W1 + l*8192;
      const float* b1l = A.b1 + l*128;
      const float* W2l = A.W2 + l*8192;
      const float* b2l = A.b2 + l*64;
      const int row0 = b*4;

      {
        const int rl = t>>6, c = t&63;
        const int row = row0 + rl;
        float mu1 = bnaccL[c]*(1.f/NB);
        float va1 = bnaccL[64+c]*(1.f/NB) - mu1*mu1;
        float mu2 = bnaccL[128+c]*(1.f/NB);
        float va2 = bnaccL[192+c]*(1.f/NB) - mu2*mu2;
        float h1 = bngL[c]*(A.s1[(size_t)row*64+c]-mu1)*rsqrtf(va1+1e-5f)+bnbL[c];
        float h2 = bngL[64+c]*(A.s2[(size_t)row*64+c]-mu2)*rsqrtf(va2+1e-5f)+bnbL[64+c];
        sm.c.sa[t] = h1+h2;
      }
      __syncthreads();
      {
        const int hj = t&127, rgq = t>>7;   // 2 rows per thread
        float a0v=b1l[hj], a1v=b1l[hj];
        #pragma unroll 4
        for (int k=0;k<64;++k){
          float w = W1l[k*128+hj];
          a0v += sm.c.sa[(rgq*2  )*64+k]*w;
          a1v += sm.c.sa[(rgq*2+1)*64+k]*w;
        }
        sm.c.sh[(rgq*2  )*128+hj] = fmaxf(a0v,0.f);
        sm.c.sh[(rgq*2+1)*128+hj] = fmaxf(a1v,0.f);
      }
      __syncthreads();
      {
        const int c = t&63, rg = t>>6;   // one row per thread
        float mo = b2l[c];
        #pragma unroll 4
        for (int k=0;k<128;++k) mo += sm.c.sh[rg*128+k]*W2l[k*64+c];
        float smv2 = sm.c.sa[rg*64+c] + mo;
        A.smlp[(size_t)(row0+rg)*64+c] = smv2;
        sm.c.S2[rg*64+c] = smv2;
      }
      __syncthreads();
      if (t<64){
        float a=0.f,aq=0.f;
        #pragma unroll
        for (int rl=0;rl<4;++rl){ float v=sm.c.S2[rl*64+t]; a+=v; aq+=v*v; }
        atomicAdd(&bnaccL[256+t],a); atomicAdd(&bnaccL[320+t],aq);
      }
    }
    gsync(A.bar + (slot++));   // bn3 stats + smlp complete
  }

  // ================= Phase out: GEMM2 + fused final bn3 =================
  {
    const float* bnacc4 = A.bnacc + 4*384;
    const float* g4 = A.bng + 896;
    const float* b4 = A.bnb + 896;
    const int rg = b>>2, cg = b&3;
    const int rows0 = rg*16;
    #pragma unroll
    for (int i=0;i<4;++i){
      int idx = t + 256*i;
      int k = idx&63, rr = idx>>6;
      float mu = bnacc4[256+k]*(1.f/NB);
      float va = bnacc4[320+k]*(1.f/NB)-mu*mu;
      sm.o.hsT[k*20+rr] = g4[k]*(A.smlp[(size_t)(rows0+rr)*64+k]-mu)*rsqrtf(va+1e-5f)+b4[k];
    }
    __syncthreads();
    const int cc = cg*1024 + t*4;
    float4 acc[16];
    {
      float4 bv = *(const float4*)&A.outb[cc];
      #pragma unroll
      for (int rr=0;rr<16;++rr) acc[rr]=bv;
    }
    #pragma unroll 4
    for (int k=0;k<64;++k){
      float4 w = *(const float4*)&A.outW[(size_t)k*4096+cc];
      const float4* hp = (const float4*)&sm.o.hsT[k*20];
      float4 h0=hp[0], h1=hp[1], h2=hp[2], h3=hp[3];
      acc[0].x+=h0.x*w.x;  acc[0].y+=h0.x*w.y;  acc[0].z+=h0.x*w.z;  acc[0].w+=h0.x*w.w;
      acc[1].x+=h0.y*w.x;  acc[1].y+=h0.y*w.y;  acc[1].z+=h0.y*w.z;  acc[1].w+=h0.y*w.w;
      acc[2].x+=h0.z*w.x;  acc[2].y+=h0.z*w.y;  acc[2].z+=h0.z*w.z;  acc[2].w+=h0.z*w.w;
      acc[3].x+=h0.w*w.x;  acc[3].y+=h0.w*w.y;  acc[3].z+=h0.w*w.z;  acc[3].w+=h0.w*w.w;
      acc[4].x+=h1.x*w.x;  acc[4].y+=h1.x*w.y;  acc[4].z+=h1.x*w.z;  acc[4].w+=h1.x*w.w;
      acc[5].x+=h1.y*w.x;  acc[5].y+=h1.y*w.y;  acc[5].z+=h1.y*w.z;  acc[5].w+=h1.y*w.w;
      acc[6].x+=h1.z*w.x;  acc[6].y+=h1.z*w.y;  acc[6].z+=h1.z*w.z;  acc[6].w+=h1.z*w.w;
      acc[7].x+=h1.w*w.x;  acc[7].y+=h1.w*w.y;  acc[7].z+=h1.w*w.z;  acc[7].w+=h1.w*w.w;
      acc[8].x+=h2.x*w.x;  acc[8].y+=h2.x*w.y;  acc[8].z+=h2.x*w.z;  acc[8].w+=h2.x*w.w;
      acc[9].x+=h2.y*w.x;  acc[9].y+=h2.y*w.y;  acc[9].z+=h2.y*w.z;  acc[9].w+=h2.y*w.w;
      acc[10].x+=h2.z*w.x; acc[10].y+=h2.z*w.y; acc[10].z+=h2.z*w.z; acc[10].w+=h2.z*w.w;
      acc[11].x+=h2.w*w.x; acc[11].y+=h2.w*w.y; acc[11].z+=h2.w*w.z; acc[11].w+=h2.w*w.w;
      acc[12].x+=h3.x*w.x; acc[12].y+=h3.x*w.y; acc[12].z+=h3.x*w.z; acc[12].w+=h3.x*w.w;
      acc[13].x+=h3.y*w.x; acc[13].y+=h3.y*w.y; acc[13].z+=h3.y*w.z; acc[13].w+=h3.y*w.w;
      acc[14].x+=h3.z*w.x; acc[14].y+=h3.z*w.y; acc[14].z+=h3.z*w.z; acc[14].w+=h3.z*w.w;
      acc[15].x+=h3.w*w.x; acc[15].y+=h3.w*w.y; acc[15].z+=h3.w*w.z; acc[15].w+=h3.w*w.w;
    }
    #pragma unroll
    for (int rr=0;rr<16;++rr)
      *(float4*)&A.out[(size_t)(rows0+rr)*4096+cc] = acc[rr];
  }
}

// ============================ host ============================

extern "C" void kernel_launch(void* const* d_in, const int* in_sizes, int n_in,
                              void* d_out, int out_size, void* d_ws, size_t ws_size,
                              hipStream_t stream)
{
  (void)in_sizes; (void)n_in; (void)out_size; (void)ws_size;
  KArgs A;
  A.x      = (const float*)d_in[0];
  A.tt     = (const float*)d_in[1];
  A.freqs  = (const float*)d_in[2];
  A.fc1W   = (const float*)d_in[3];
  A.fc1b   = (const float*)d_in[4];
  A.fc2W   = (const float*)d_in[5];
  A.fc2b   = (const float*)d_in[6];
  A.nodeW  = (const float*)d_in[7];
  A.nodeb  = (const float*)d_in[8];
  A.tprojW = (const float*)d_in[9];
  A.tprojb = (const float*)d_in[10];
  A.tcatW  = (const float*)d_in[11];
  A.tcatb  = (const float*)d_in[12];
  A.penb   = (const float*)d_in[14];
  A.pelW   = (const float*)d_in[15];
  A.pelb   = (const float*)d_in[16];
  A.catW   = (const float*)d_in[17];
  A.catb   = (const float*)d_in[18];
  A.convWg = (const float*)d_in[19];
  A.gruWih = (const float*)d_in[20];
  A.grubih = (const float*)d_in[21];
  A.gruWhh = (const float*)d_in[22];
  A.grubhh = (const float*)d_in[23];
  A.Wqkv   = (const float*)d_in[24];
  A.bqkv   = (const float*)d_in[25];
  A.Wo     = (const float*)d_in[26];
  A.bo     = (const float*)d_in[27];
  A.bng    = (const float*)d_in[28];
  A.bnb    = (const float*)d_in[29];
  A.W1     = (const float*)d_in[30];
  A.b1     = (const float*)d_in[31];
  A.W2     = (const float*)d_in[32];
  A.b2     = (const float*)d_in[33];
  A.outW   = (const float*)d_in[34];
  A.outb   = (const float*)d_in[35];

  float* ws = (float*)d_ws;
  A.htime = ws;                      // 131072
  A.hbuf  = A.htime + 131072;        // 131072
  A.gh    = A.hbuf + 131072;         // 393216
  A.s1    = A.gh + 393216;           // 131072
  A.s2    = A.s1 + 131072;           // 131072
  A.smlp  = A.s2 + 131072;           // 131072
  A.o_out = A.smlp + 131072;         // 131072
  A.hsum  = A.o_out + 131072;        // 320
  A.bnacc = A.hsum + 320;            // 1920
  A.Qb = (unsigned short*)(A.bnacc + 1920);   // 262144 ushort
  A.Kb = A.Qb + 262144;                       // 262144 ushort
  A.Vt = A.Kb + 262144;                       // 65536 ushort
  A.h0p  = (float*)(A.Vt + 65536);   // fused path uses slots 0..3 (4*131072)
  A.bar  = (unsigned*)(A.h0p + 4*(NB*HDM));   // 64 u32 barrier slots, inside proven ws
  A.out  = (float*)d_out;

  hipMemsetAsync(A.bar, 0, 64*sizeof(unsigned), stream);
  k_fused<<<dim3(NBLK), dim3(256), 0, stream>>>(A);
}

// Round 4
// 857.382 us; speedup vs baseline: 1.2988x; 1.2988x over previous
//
#include <hip/hip_runtime.h>

#define NB 2048
#define HDM 64
#define NLAY 5
#define NBLK 512

typedef __bf16 bf16x8 __attribute__((ext_vector_type(8)));
typedef float v4f __attribute__((ext_vector_type(4)));

__device__ __forceinline__ float sigmoidf_(float x){ return 1.f/(1.f+__expf(-x)); }
__device__ __forceinline__ float tanhfast_(float x){
  x = fminf(fmaxf(x, -15.f), 15.f);
  float e = __expf(2.f*x);
  return (e-1.f)/(e+1.f);
}
__device__ __forceinline__ unsigned short f2b_rne(float f){
  unsigned u = __float_as_uint(f);
  unsigned r = u + 0x7FFFu + ((u>>16)&1u);
  return (unsigned short)(r>>16);
}
__device__ __forceinline__ unsigned pk2(float a, float b){
  unsigned ua = (__float_as_uint(a) + 0x8000u) >> 16;
  unsigned ub = (__float_as_uint(b) + 0x8000u) & 0xFFFF0000u;
  return ua | ub;
}

// ---------- device-coherent (sc0 sc1) access helpers ----------
// Cross-XCD-shared arrays (h0p, Qb, Kb, Vt, o_out, smlp, hsum/bnacc-zeroing) are accessed
// ONLY through these: stores are write-through to the coherent point (never dirty in a
// non-coherent per-XCD L2), loads bypass L1/L2. This removes the need for any
// buffer_wbl2/buffer_inv at grid barriers -> barriers become pure counters and the L2
// stays warm with weights for the entire kernel.

__device__ __forceinline__ float ld_f32_sc(const float* p){
  float v;
  asm volatile("global_load_dword %0, %1, off sc0 sc1\n"
               "s_waitcnt vmcnt(0)"
               : "=v"(v) : "v"(p) : "memory");
  return v;
}
__device__ __forceinline__ void ld4_f32_sc(float& a, float& b, float& c, float& d,
                                           const float* p0, const float* p1,
                                           const float* p2, const float* p3){
  asm volatile("global_load_dword %0, %4, off sc0 sc1\n"
               "global_load_dword %1, %5, off sc0 sc1\n"
               "global_load_dword %2, %6, off sc0 sc1\n"
               "global_load_dword %3, %7, off sc0 sc1\n"
               "s_waitcnt vmcnt(0)"
               : "=&v"(a), "=&v"(b), "=&v"(c), "=&v"(d)
               : "v"(p0), "v"(p1), "v"(p2), "v"(p3) : "memory");
}
__device__ __forceinline__ bf16x8 ld_b16x8_sc_wait(const unsigned short* p){
  bf16x8 v;
  asm volatile("global_load_dwordx4 %0, %1, off sc0 sc1\n"
               "s_waitcnt vmcnt(0)"
               : "=v"(v) : "v"(p) : "memory");
  return v;
}
__device__ __forceinline__ void ld3_b16x8_sc(bf16x8& a, bf16x8& b, bf16x8& c,
                                             const unsigned short* pa,
                                             const unsigned short* pb,
                                             const unsigned short* pc){
  asm volatile("global_load_dwordx4 %0, %3, off sc0 sc1\n"
               "global_load_dwordx4 %1, %4, off sc0 sc1\n"
               "global_load_dwordx4 %2, %5, off sc0 sc1"
               : "=&v"(a), "=&v"(b), "=&v"(c)
               : "v"(pa), "v"(pb), "v"(pc) : "memory");
}
// waitcnt tied to the loaded values ("+v") so the compiler cannot schedule a consumer
// (MFMA reads these regs) above the wait (guide rule #18).
__device__ __forceinline__ void await3(bf16x8& a, bf16x8& b, bf16x8& c){
  asm volatile("s_waitcnt vmcnt(0)" : "+v"(a), "+v"(b), "+v"(c) :: "memory");
  __builtin_amdgcn_sched_barrier(0);
}
__device__ __forceinline__ void st_f32_sc(float* p, float v){
  asm volatile("global_store_dword %0, %1, off sc0 sc1" :: "v"(p), "v"(v) : "memory");
}
__device__ __forceinline__ void st_v4f_sc(float* p, v4f v){
  asm volatile("global_store_dwordx4 %0, %1, off sc0 sc1" :: "v"(p), "v"(v) : "memory");
}
__device__ __forceinline__ void st_u16_sc(unsigned short* p, unsigned short v){
  unsigned vv = v;
  asm volatile("global_store_short %0, %1, off sc0 sc1" :: "v"(p), "v"(vv) : "memory");
}

// ============================ fused kernel ============================
// 512 blocks x 256 threads, __launch_bounds__(256,2): 2 blocks/CU * 256 CU = 512 resident.

struct KArgs {
  const float *x, *tt, *freqs, *fc1W, *fc1b, *fc2W, *fc2b, *nodeW, *nodeb,
              *tprojW, *tprojb, *tcatW, *tcatb, *penb, *pelW, *pelb, *catW, *catb,
              *convWg, *gruWih, *grubih, *gruWhh, *grubhh, *Wqkv, *bqkv, *Wo, *bo,
              *bng, *bnb, *W1, *b1, *W2, *b2, *outW, *outb;
  float *htime, *hbuf, *gh, *s1, *s2, *smlp, *o_out, *hsum, *bnacc, *h0p, *out;
  unsigned short *Qb, *Kb, *Vt;
  unsigned *bar;
};

union SMem {
  struct { float xs[16*260]; float tb0[256]; float tb1[256]; } pre;             // 18688 B
  struct { float sa[256]; float sb[256]; float cvec[64]; } as;                  // 2304 B
  struct { float sa[256]; } a;                                                  // 1024 B
  struct { unsigned short Pl[4*640]; float Os[4*272]; float ms[64]; float ls[64]; } at; // 9984 B
  struct { float sa[256]; float os[256]; float smv[64]; float sgi[192]; float Sb1[256]; float Sb2[256]; } b2; // 5120 B
  struct { float sa[256]; float sh[4*128]; float S2[256]; } c;                  // 4096 B
  struct { float hsT[64*20]; } o;                                               // 5120 B
};

// Pure-counter grid sync: NO cache maintenance (rounds 2/3 showed per-block
// wbl2/inv fences cost ~45us/barrier; all cross-block data now goes through the
// coherent point via sc0sc1 accesses, so no fence is needed at all).
// Release ordering is structural: every wave drains its own vmcnt before the
// s_barrier, and thread 0 arrives only after the barrier.
__device__ __forceinline__ void gsync(unsigned* slotp){
  asm volatile("s_waitcnt vmcnt(0)" ::: "memory");   // drain this wave's sc-stores
  __syncthreads();
  if (threadIdx.x == 0){
    __hip_atomic_fetch_add(slotp, 1u, __ATOMIC_RELAXED, __HIP_MEMORY_SCOPE_AGENT);
    unsigned spins = 0u;
    while (__hip_atomic_load(slotp, __ATOMIC_RELAXED, __HIP_MEMORY_SCOPE_AGENT) < (unsigned)NBLK){
      __builtin_amdgcn_s_sleep(8);
      if (++spins > 1000000u) break;   // fail loud (wrong data), never hang
    }
    asm volatile("" ::: "memory");
  }
  __syncthreads();
}

__global__ __launch_bounds__(256, 2) void k_fused(KArgs A)
{
  __shared__ SMem sm;
  const int t = threadIdx.x;
  const int b = blockIdx.x;
  int slot = 0;

  // ================= Phase P: zero accumulators + time-embedding + GEMM1 =================
  if (b == 0){
    for (int i = t; i < 320 + 1920; i += 256) st_f32_sc(&A.hsum[i], 0.f);  // hsum+bnacc
  }
  {
    // time embedding for rows b*4 + r
    const int r = t>>6, c = t&63;
    const int row = b*4 + r;
    const float tv = A.tt[row];
    float te[16];
    #pragma unroll
    for (int j=0;j<8;++j){
      float sv, cv;
      __sincosf(6.28318530717958647692f*tv*A.freqs[j], &sv, &cv);
      te[j]=sv; te[j+8]=cv;
    }
    float a = A.fc1b[c];
    #pragma unroll
    for (int j=0;j<16;++j) a += te[j]*A.fc1W[j*64+c];
    sm.pre.tb0[r*64+c] = a*sigmoidf_(a);
    __syncthreads();
    float b2v = A.fc2b[c];
    #pragma unroll 8
    for (int k=0;k<64;++k) b2v += sm.pre.tb0[r*64+k]*A.fc2W[k*64+c];
    sm.pre.tb1[r*64+c] = b2v;
    __syncthreads();
    float hti = A.tprojb[c];
    #pragma unroll 8
    for (int k=0;k<64;++k) hti += sm.pre.tb1[r*64+k]*A.tprojW[k*64+c];
    A.htime[row*64+c] = hti;               // block-private: plain store
  }
  {
    // GEMM1 partial: rowgroup rg = b>>2 (16 rows), K-quarter kq = b&3 (1024 k)
    const int rg = b>>2, kq = b&3;
    const int rows0 = rg*16, k0 = kq*1024;
    const int col4 = (t&15)*4;
    const int rq4  = ((t>>4)&3)*4;
    const int ksub = (t>>6)*64;

    float4 a0={0,0,0,0}, a1={0,0,0,0}, a2={0,0,0,0}, a3={0,0,0,0};

    for (int ch=0; ch<4; ++ch){
      __syncthreads();
      #pragma unroll
      for (int i=0;i<4;++i){
        int fi = t + 256*i;
        int xr = fi>>6, kk = (fi&63)<<2;
        *(float4*)&sm.pre.xs[xr*260+kk] =
            *(const float4*)&A.x[(size_t)(rows0+xr)*4096 + k0 + ch*256 + kk];
      }
      __syncthreads();
      const float* wp = &A.nodeW[(size_t)(k0 + ch*256 + ksub)*64 + col4];
      const float* xp = &sm.pre.xs[rq4*260 + ksub];
      #pragma unroll 8
      for (int kk=0; kk<64; ++kk){
        float4 w  = *(const float4*)&wp[kk*64];
        float x0 = xp[kk];
        float x1 = xp[260+kk];
        float x2 = xp[520+kk];
        float x3 = xp[780+kk];
        a0.x += x0*w.x; a0.y += x0*w.y; a0.z += x0*w.z; a0.w += x0*w.w;
        a1.x += x1*w.x; a1.y += x1*w.y; a1.z += x1*w.z; a1.w += x1*w.w;
        a2.x += x2*w.x; a2.y += x2*w.y; a2.z += x2*w.z; a2.w += x2*w.w;
        a3.x += x3*w.x; a3.y += x3*w.y; a3.z += x3*w.z; a3.w += x3*w.w;
      }
    }
    __syncthreads();
    {
      const int kqi = t>>6;
      *(float4*)&sm.pre.xs[(kqi*16 + rq4 + 0)*64 + col4] = a0;
      *(float4*)&sm.pre.xs[(kqi*16 + rq4 + 1)*64 + col4] = a1;
      *(float4*)&sm.pre.xs[(kqi*16 + rq4 + 2)*64 + col4] = a2;
      *(float4*)&sm.pre.xs[(kqi*16 + rq4 + 3)*64 + col4] = a3;
    }
    __syncthreads();
    {
      const int row = t>>4, c4 = (t&15)*4;
      float4 s = {0,0,0,0};
      #pragma unroll
      for (int q=0;q<4;++q){
        float4 v = *(const float4*)&sm.pre.xs[(q*16+row)*64 + c4];
        s.x+=v.x; s.y+=v.y; s.z+=v.z; s.w+=v.w;
      }
      v4f sv = {s.x, s.y, s.z, s.w};
      st_v4f_sc(&A.h0p[(size_t)kq*(NB*HDM) + (rows0+row)*64 + c4], sv);  // cross-block
    }
  }
  gsync(A.bar + (slot++));   // all GEMM1 partials + zeroing at coherent point

  // ================= Phase assemble: rows b*4 + r =================
  {
    const int r = t>>6, c = t&63;
    const int row = b*4 + r;
    if (r==0){
      float pl[16];
      #pragma unroll
      for (int j=0;j<16;++j){
        float a = A.pelb[j];
        for (int w=0;w<20;++w) a += A.penb[w]*A.pelW[w*16+j];
        pl[j]=a;
      }
      float a = A.catb[c];
      #pragma unroll
      for (int j=0;j<16;++j) a += pl[j]*A.catW[(64+j)*64+c];
      sm.as.cvec[c]=a;
    }
    float p0,p1,p2,p3;
    ld4_f32_sc(p0,p1,p2,p3,
               &A.h0p[0*(NB*HDM) + row*64 + c], &A.h0p[1*(NB*HDM) + row*64 + c],
               &A.h0p[2*(NB*HDM) + row*64 + c], &A.h0p[3*(NB*HDM) + row*64 + c]);
    sm.as.sa[t] = A.nodeb[c] + ((p0+p1)+(p2+p3));
    sm.as.sb[t] = A.htime[row*64+c];       // block-private
    __syncthreads();
    float a = A.tcatb[c];
    #pragma unroll 4
    for (int k=0;k<64;++k){
      a += sm.as.sa[r*64+k]*A.tcatW[k*64+c];
      a += sm.as.sb[r*64+k]*A.tcatW[(64+k)*64+c];
    }
    __syncthreads();
    sm.as.sa[t] = a;
    __syncthreads();
    float hv = sm.as.cvec[c];
    #pragma unroll 8
    for (int k=0;k<64;++k) hv += sm.as.sa[r*64+k]*A.catW[k*64+c];
    A.hbuf[row*64+c] = hv;                 // block-private
  }
  // no grid sync: layer-0 phase A reads only this block's own rows of hbuf

  // ================= layers =================
  for (int l=0; l<NLAY; ++l){
    const float* bnaccPrev = (l==0) ? A.bnacc : A.bnacc + (l-1)*384;
    const float* gPrev = (l==0) ? A.bng : A.bng + (l-1)*192 + 128;
    const float* bPrev = (l==0) ? A.bnb : A.bnb + (l-1)*192 + 128;
    const float* Whh = A.gruWhh + l*12288;
    const float* bhh = A.grubhh + l*192;
    const float* Wq  = A.Wqkv + l*12288;
    const float* bqv = A.bqkv + l*192;
    float* hsumL  = A.hsum + l*64;
    float* bnaccL = A.bnacc + l*384;

    // ---- Phase A: [bn3 prev] + hsum + gh + bf16 QKV packs (4 rows) ----
    __syncthreads();   // protect LDS union reuse
    {
      const int row0 = b*4;
      const int rl = t>>6, c = t&63;
      const int row = row0 + rl;
      float hv;
      if (l==0){
        hv = A.hbuf[row*64+c];             // block-private
      } else {
        float mu = bnaccPrev[256+c]*(1.f/NB);          // first-touch lines: plain ok
        float va = bnaccPrev[320+c]*(1.f/NB) - mu*mu;
        float sv = ld_f32_sc(&A.smlp[row*64+c]);       // rewritten by self via sc: sc read
        hv = gPrev[c]*(sv-mu)*rsqrtf(va+1e-5f)+bPrev[c];
        A.hbuf[row*64+c] = hv;             // block-private
      }
      sm.a.sa[t] = hv;
      __syncthreads();
      if (t<64){
        float s = sm.a.sa[t]+sm.a.sa[64+t]+sm.a.sa[128+t]+sm.a.sa[192+t];
        atomicAdd(&hsumL[t], s);           // device-scope atomic: coherent point
      }
      if (t < 192){
        const int cc = t;
        float ag[4], aq[4];
        float bh = bhh[cc], bq_ = bqv[cc];
        #pragma unroll
        for (int rl2=0;rl2<4;++rl2){ ag[rl2]=bh; aq[rl2]=bq_; }
        #pragma unroll 4
        for (int k=0;k<64;++k){
          float wh = Whh[k*192+cc];
          float wq = Wq [k*192+cc];
          #pragma unroll
          for (int rl2=0;rl2<4;++rl2){
            float hk = sm.a.sa[rl2*64+k];
            ag[rl2] += hk*wh;
            aq[rl2] += hk*wq;
          }
        }
        #pragma unroll
        for (int rl2=0;rl2<4;++rl2){
          int rw = row0 + rl2;
          A.gh[(size_t)rw*192+cc] = ag[rl2];           // block-private
          float aqv = aq[rl2];
          if (cc < 64){
            int hd = cc>>4, dh = cc&15;
            size_t base = ((size_t)(hd<<11) + rw)*32;
            st_u16_sc(&A.Qb[base+dh], f2b_rne(aqv*0.25f));
            st_u16_sc(&A.Qb[base+16+dh], (unsigned short)0);
          } else if (cc < 128){
            int c2 = cc-64, hd = c2>>4, dh = c2&15;
            size_t base = ((size_t)(hd<<11) + rw)*32;
            st_u16_sc(&A.Kb[base+dh], f2b_rne(aqv));
            st_u16_sc(&A.Kb[base+16+dh], (unsigned short)0);
          } else {
            int c2 = cc-128, hd = c2>>4, dh = c2&15;
            st_u16_sc(&A.Vt[((size_t)(hd*16+dh))*2048 + rw], f2b_rne(aqv));
          }
        }
      }
    }
    gsync(A.bar + (slot++));   // QKV at coherent point

    // ---- Phase attn: unit b = (qt = b&127, head = b>>7), 4 waves x 512 keys ----
    {
      const int w = t>>6, lane = t&63;
      const int q15 = lane & 15, quad = lane >> 4;
      const int qt = b & 127, head = b>>7;
      const int qrow = qt*16 + q15;
      const int key00 = w*512;
      unsigned short* Plw = &sm.at.Pl[w*640];

      const bf16x8 qf = ld_b16x8_sc_wait(&A.Qb[(((size_t)(head<<11))+qrow)*32 + quad*8]);
      const unsigned short* Kb_h = A.Kb + ((size_t)(head<<11))*32;
      const unsigned short* Vrow = A.Vt + ((size_t)(head*16+q15))*2048;

      v4f O = {0.f,0.f,0.f,0.f};
      float m = -1e30f, lsum = 0.f;

      bf16x8 kf0, kf1, vf;
      ld3_b16x8_sc(kf0, kf1, vf,
                   &Kb_h[(size_t)(key00 + q15)*32 + quad*8],
                   &Kb_h[(size_t)(key00 + 16 + q15)*32 + quad*8],
                   &Vrow[key00 + quad*8]);
      await3(kf0, kf1, vf);

      for (int c=0; c<16; ++c){
        bf16x8 nk0, nk1, nv;
        if (c < 15){
          int nk = key00 + (c+1)*32;
          ld3_b16x8_sc(nk0, nk1, nv,
                       &Kb_h[(size_t)(nk + q15)*32 + quad*8],
                       &Kb_h[(size_t)(nk + 16 + q15)*32 + quad*8],
                       &Vrow[nk + quad*8]);
        }
        v4f z = {0.f,0.f,0.f,0.f};
        v4f s0 = __builtin_amdgcn_mfma_f32_16x16x32_bf16(kf0, qf, z, 0,0,0);
        v4f s1 = __builtin_amdgcn_mfma_f32_16x16x32_bf16(kf1, qf, z, 0,0,0);
        float cmax = fmaxf(fmaxf(fmaxf(s0[0],s0[1]),fmaxf(s0[2],s0[3])),
                           fmaxf(fmaxf(s1[0],s1[1]),fmaxf(s1[2],s1[3])));
        cmax = fmaxf(cmax, __shfl_xor(cmax,16,64));
        cmax = fmaxf(cmax, __shfl_xor(cmax,32,64));
        float mnew = fmaxf(m, cmax);
        float alpha = __expf(m - mnew);
        float p0=__expf(s0[0]-mnew), p1=__expf(s0[1]-mnew), p2=__expf(s0[2]-mnew), p3=__expf(s0[3]-mnew);
        float p4=__expf(s1[0]-mnew), p5=__expf(s1[1]-mnew), p6=__expf(s1[2]-mnew), p7=__expf(s1[3]-mnew);
        lsum = alpha*lsum + ((p0+p1)+(p2+p3)+((p4+p5)+(p6+p7)));
        m = mnew;
        O[0]*=alpha; O[1]*=alpha; O[2]*=alpha; O[3]*=alpha;
        *(uint2*)&Plw[q15*40 + quad*4]      = make_uint2(pk2(p0,p1), pk2(p2,p3));
        *(uint2*)&Plw[q15*40 + 16 + quad*4] = make_uint2(pk2(p4,p5), pk2(p6,p7));
        asm volatile("s_waitcnt lgkmcnt(0)" ::: "memory");
        bf16x8 pf = *(const bf16x8*)&Plw[q15*40 + quad*8];
        O = __builtin_amdgcn_mfma_f32_16x16x32_bf16(vf, pf, O, 0,0,0);
        if (c < 15){
          kf0 = nk0; kf1 = nk1; vf = nv;
          await3(kf0, kf1, vf);
        }
      }
      lsum += __shfl_xor(lsum,16,64);
      lsum += __shfl_xor(lsum,32,64);
      #pragma unroll
      for (int j=0;j<4;++j) sm.at.Os[w*272 + q15*17 + quad*4 + j] = O[j];
      if (quad==0){ sm.at.ms[w*16+q15]=m; sm.at.ls[w*16+q15]=lsum; }
      __syncthreads();
      {
        const int dh = t&15, q = t>>4;
        float m0=sm.at.ms[q], m1=sm.at.ms[16+q], m2=sm.at.ms[32+q], m3=sm.at.ms[48+q];
        float mm = fmaxf(fmaxf(m0,m1),fmaxf(m2,m3));
        float a0=__expf(m0-mm), a1=__expf(m1-mm), a2=__expf(m2-mm), a3=__expf(m3-mm);
        float ll = a0*sm.at.ls[q]+a1*sm.at.ls[16+q]+a2*sm.at.ls[32+q]+a3*sm.at.ls[48+q];
        float oo = a0*sm.at.Os[q*17+dh] + a1*sm.at.Os[272+q*17+dh]
                 + a2*sm.at.Os[544+q*17+dh] + a3*sm.at.Os[816+q*17+dh];
        st_f32_sc(&A.o_out[(size_t)(qt*16+q)*64 + head*16 + dh], oo / ll);  // cross-block
      }
    }
    gsync(A.bar + (slot++));   // o_out at coherent point

    // ---- Phase B2: o-proj + GRU + bn1/bn2 stats (4 rows) ----
    {
      const float* Wg  = A.convWg + l*4096;
      const float* Wih = A.gruWih + l*12288;
      const float* bih = A.grubih + l*192;
      const float* WoL = A.Wo + l*4096;
      const float* boL = A.bo + l*64;
      const int row0 = b*4;

      if (t<64){
        float a=0.f;
        #pragma unroll 8
        for (int k=0;k<64;++k) a += hsumL[k]*Wg[k*64+t];   // hsum: first-touch, atomics at L3
        sm.b2.smv[t]=a;
      }
      {
        const int rl = t>>6, c = t&63;
        sm.b2.sa[t] = A.hbuf[(size_t)(row0+rl)*64+c];                 // block-private
        sm.b2.os[t] = ld_f32_sc(&A.o_out[(size_t)(row0+rl)*64+c]);    // cross-block
      }
      __syncthreads();
      if (t<192){
        float a = bih[t];
        #pragma unroll 8
        for (int k=0;k<64;++k) a += sm.b2.smv[k]*Wih[k*192+t];
        sm.b2.sgi[t]=a;
      }
      __syncthreads();

      {
        const int c = t&63, rg = t>>6;   // one row per thread
        float o2 = boL[c];
        #pragma unroll 4
        for (int k=0;k<64;++k) o2 += sm.b2.os[rg*64+k]*WoL[k*64+c];
        const int row = row0 + rg;
        float hv = sm.b2.sa[rg*64+c];
        float s2v = o2 + hv;
        float ir = sm.b2.sgi[c]      + A.gh[(size_t)row*192+c];
        float iz = sm.b2.sgi[64+c]   + A.gh[(size_t)row*192+64+c];
        float inn = sm.b2.sgi[128+c];
        float hn  = A.gh[(size_t)row*192+128+c];
        float rr_ = sigmoidf_(ir);
        float zz  = sigmoidf_(iz);
        float nn  = tanhfast_(inn + rr_*hn);
        float s1v = (1.f-zz)*nn + zz*hv + hv;   // hc + h
        A.s1[(size_t)row*64+c] = s1v;           // block-private
        A.s2[(size_t)row*64+c] = s2v;           // block-private
        sm.b2.Sb1[rg*64+c] = s1v;
        sm.b2.Sb2[rg*64+c] = s2v;
      }
      __syncthreads();
      if (t<64){
        float a=0.f,aq=0.f,bb=0.f,bq2=0.f;
        #pragma unroll
        for (int rl=0;rl<4;++rl){
          float v1 = sm.b2.Sb1[rl*64+t], v2 = sm.b2.Sb2[rl*64+t];
          a+=v1; aq+=v1*v1; bb+=v2; bq2+=v2*v2;
        }
        atomicAdd(&bnaccL[t],a);     atomicAdd(&bnaccL[64+t],aq);
        atomicAdd(&bnaccL[128+t],bb); atomicAdd(&bnaccL[192+t],bq2);
      }
    }
    gsync(A.bar + (slot++));   // bn1/bn2 stats complete

    // ---- Phase C: bn1/bn2 apply + MLP + bn3 stats (4 rows) ----
    {
      const float* bngL = A.bng + l*192;
      const float* bnbL = A.bnb + l*192;
      const float* W1l = A.W1 + l*8192;
      const float* b1l = A.b1 + l*128;
      const float* W2l = A.W2 + l*8192;
      const float* b2l = A.b2 + l*64;
      const int row0 = b*4;

      {
        const int rl = t>>6, c = t&63;
        const int row = row0 + rl;
        float mu1 = bnaccL[c]*(1.f/NB);            // first-touch lines: plain ok
        float va1 = bnaccL[64+c]*(1.f/NB) - mu1*mu1;
        float mu2 = bnaccL[128+c]*(1.f/NB);
        float va2 = bnaccL[192+c]*(1.f/NB) - mu2*mu2;
        float h1 = bngL[c]*(A.s1[(size_t)row*64+c]-mu1)*rsqrtf(va1+1e-5f)+bnbL[c];
        float h2 = bngL[64+c]*(A.s2[(size_t)row*64+c]-mu2)*rsqrtf(va2+1e-5f)+bnbL[64+c];
        sm.c.sa[t] = h1+h2;
      }
      __syncthreads();
      {
        const int hj = t&127, rgq = t>>7;   // 2 rows per thread
        float a0v=b1l[hj], a1v=b1l[hj];
        #pragma unroll 4
        for (int k=0;k<64;++k){
          float w = W1l[k*128+hj];
          a0v += sm.c.sa[(rgq*2  )*64+k]*w;
          a1v += sm.c.sa[(rgq*2+1)*64+k]*w;
        }
        sm.c.sh[(rgq*2  )*128+hj] = fmaxf(a0v,0.f);
        sm.c.sh[(rgq*2+1)*128+hj] = fmaxf(a1v,0.f);
      }
      __syncthreads();
      {
        const int c = t&63, rg = t>>6;   // one row per thread
        float mo = b2l[c];
        #pragma unroll 4
        for (int k=0;k<128;++k) mo += sm.c.sh[rg*128+k]*W2l[k*64+c];
        float smv2 = sm.c.sa[rg*64+c] + mo;
        st_f32_sc(&A.smlp[(size_t)(row0+rg)*64+c], smv2);   // cross-block (GEMM2) + self
        sm.c.S2[rg*64+c] = smv2;
      }
      __syncthreads();
      if (t<64){
        float a=0.f,aq=0.f;
        #pragma unroll
        for (int rl=0;rl<4;++rl){ float v=sm.c.S2[rl*64+t]; a+=v; aq+=v*v; }
        atomicAdd(&bnaccL[256+t],a); atomicAdd(&bnaccL[320+t],aq);
      }
    }
    gsync(A.bar + (slot++));   // bn3 stats + smlp at coherent point
  }

  // ================= Phase out: GEMM2 + fused final bn3 =================
  {
    const float* bnacc4 = A.bnacc + 4*384;
    const float* g4 = A.bng + 896;
    const float* b4 = A.bnb + 896;
    const int rg = b>>2, cg = b&3;
    const int rows0 = rg*16;
    {
      float s0,s1v,s2v,s3;
      const int i0=t, i1=t+256, i2=t+512, i3=t+768;
      ld4_f32_sc(s0,s1v,s2v,s3,
                 &A.smlp[(size_t)(rows0+(i0>>6))*64+(i0&63)],
                 &A.smlp[(size_t)(rows0+(i1>>6))*64+(i1&63)],
                 &A.smlp[(size_t)(rows0+(i2>>6))*64+(i2&63)],
                 &A.smlp[(size_t)(rows0+(i3>>6))*64+(i3&63)]);
      float sv[4] = {s0,s1v,s2v,s3};
      #pragma unroll
      for (int i=0;i<4;++i){
        int idx = t + 256*i;
        int k = idx&63, rr = idx>>6;
        float mu = bnacc4[256+k]*(1.f/NB);
        float va = bnacc4[320+k]*(1.f/NB)-mu*mu;
        sm.o.hsT[k*20+rr] = g4[k]*(sv[i]-mu)*rsqrtf(va+1e-5f)+b4[k];
      }
    }
    __syncthreads();
    const int cc = cg*1024 + t*4;
    float4 acc[16];
    {
      float4 bv = *(const float4*)&A.outb[cc];
      #pragma unroll
      for (int rr=0;rr<16;++rr) acc[rr]=bv;
    }
    #pragma unroll 4
    for (int k=0;k<64;++k){
      float4 w = *(const float4*)&A.outW[(size_t)k*4096+cc];
      const float4* hp = (const float4*)&sm.o.hsT[k*20];
      float4 h0=hp[0], h1=hp[1], h2=hp[2], h3=hp[3];
      acc[0].x+=h0.x*w.x;  acc[0].y+=h0.x*w.y;  acc[0].z+=h0.x*w.z;  acc[0].w+=h0.x*w.w;
      acc[1].x+=h0.y*w.x;  acc[1].y+=h0.y*w.y;  acc[1].z+=h0.y*w.z;  acc[1].w+=h0.y*w.w;
      acc[2].x+=h0.z*w.x;  acc[2].y+=h0.z*w.y;  acc[2].z+=h0.z*w.z;  acc[2].w+=h0.z*w.w;
      acc[3].x+=h0.w*w.x;  acc[3].y+=h0.w*w.y;  acc[3].z+=h0.w*w.z;  acc[3].w+=h0.w*w.w;
      acc[4].x+=h1.x*w.x;  acc[4].y+=h1.x*w.y;  acc[4].z+=h1.x*w.z;  acc[4].w+=h1.x*w.w;
      acc[5].x+=h1.y*w.x;  acc[5].y+=h1.y*w.y;  acc[5].z+=h1.y*w.z;  acc[5].w+=h1.y*w.w;
      acc[6].x+=h1.z*w.x;  acc[6].y+=h1.z*w.y;  acc[6].z+=h1.z*w.z;  acc[6].w+=h1.z*w.w;
      acc[7].x+=h1.w*w.x;  acc[7].y+=h1.w*w.y;  acc[7].z+=h1.w*w.z;  acc[7].w+=h1.w*w.w;
      acc[8].x+=h2.x*w.x;  acc[8].y+=h2.x*w.y;  acc[8].z+=h2.x*w.z;  acc[8].w+=h2.x*w.w;
      acc[9].x+=h2.y*w.x;  acc[9].y+=h2.y*w.y;  acc[9].z+=h2.y*w.z;  acc[9].w+=h2.y*w.w;
      acc[10].x+=h2.z*w.x; acc[10].y+=h2.z*w.y; acc[10].z+=h2.z*w.z; acc[10].w+=h2.z*w.w;
      acc[11].x+=h2.w*w.x; acc[11].y+=h2.w*w.y; acc[11].z+=h2.w*w.z; acc[11].w+=h2.w*w.w;
      acc[12].x+=h3.x*w.x; acc[12].y+=h3.x*w.y; acc[12].z+=h3.x*w.z; acc[12].w+=h3.x*w.w;
      acc[13].x+=h3.y*w.x; acc[13].y+=h3.y*w.y; acc[13].z+=h3.y*w.z; acc[13].w+=h3.y*w.w;
      acc[14].x+=h3.z*w.x; acc[14].y+=h3.z*w.y; acc[14].z+=h3.z*w.z; acc[14].w+=h3.z*w.w;
      acc[15].x+=h3.w*w.x; acc[15].y+=h3.w*w.y; acc[15].z+=h3.w*w.z; acc[15].w+=h3.w*w.w;
    }
    #pragma unroll
    for (int rr=0;rr<16;++rr)
      *(float4*)&A.out[(size_t)(rows0+rr)*4096+cc] = acc[rr];   // kernel-end release flushes
  }
}

// ============================ host ============================

extern "C" void kernel_launch(void* const* d_in, const int* in_sizes, int n_in,
                              void* d_out, int out_size, void* d_ws, size_t ws_size,
                              hipStream_t stream)
{
  (void)in_sizes; (void)n_in; (void)out_size; (void)ws_size;
  KArgs A;
  A.x      = (const float*)d_in[0];
  A.tt     = (const float*)d_in[1];
  A.freqs  = (const float*)d_in[2];
  A.fc1W   = (const float*)d_in[3];
  A.fc1b   = (const float*)d_in[4];
  A.fc2W   = (const float*)d_in[5];
  A.fc2b   = (const float*)d_in[6];
  A.nodeW  = (const float*)d_in[7];
  A.nodeb  = (const float*)d_in[8];
  A.tprojW = (const float*)d_in[9];
  A.tprojb = (const float*)d_in[10];
  A.tcatW  = (const float*)d_in[11];
  A.tcatb  = (const float*)d_in[12];
  A.penb   = (const float*)d_in[14];
  A.pelW   = (const float*)d_in[15];
  A.pelb   = (const float*)d_in[16];
  A.catW   = (const float*)d_in[17];
  A.catb   = (const float*)d_in[18];
  A.convWg = (const float*)d_in[19];
  A.gruWih = (const float*)d_in[20];
  A.grubih = (const float*)d_in[21];
  A.gruWhh = (const float*)d_in[22];
  A.grubhh = (const float*)d_in[23];
  A.Wqkv   = (const float*)d_in[24];
  A.bqkv   = (const float*)d_in[25];
  A.Wo     = (const float*)d_in[26];
  A.bo     = (const float*)d_in[27];
  A.bng    = (const float*)d_in[28];
  A.bnb    = (const float*)d_in[29];
  A.W1     = (const float*)d_in[30];
  A.b1     = (const float*)d_in[31];
  A.W2     = (const float*)d_in[32];
  A.b2     = (const float*)d_in[33];
  A.outW   = (const float*)d_in[34];
  A.outb   = (const float*)d_in[35];

  float* ws = (float*)d_ws;
  A.htime = ws;                      // 131072
  A.hbuf  = A.htime + 131072;        // 131072
  A.gh    = A.hbuf + 131072;         // 393216
  A.s1    = A.gh + 393216;           // 131072
  A.s2    = A.s1 + 131072;           // 131072
  A.smlp  = A.s2 + 131072;           // 131072
  A.o_out = A.smlp + 131072;         // 131072
  A.hsum  = A.o_out + 131072;        // 320
  A.bnacc = A.hsum + 320;            // 1920
  A.Qb = (unsigned short*)(A.bnacc + 1920);   // 262144 ushort
  A.Kb = A.Qb + 262144;                       // 262144 ushort
  A.Vt = A.Kb + 262144;                       // 65536 ushort
  A.h0p  = (float*)(A.Vt + 65536);   // fused path uses slots 0..3 (4*131072)
  A.bar  = (unsigned*)(A.h0p + 4*(NB*HDM));   // 64 u32 barrier slots, inside proven ws
  A.out  = (float*)d_out;

  hipMemsetAsync(A.bar, 0, 64*sizeof(unsigned), stream);
  k_fused<<<dim3(NBLK), dim3(256), 0, stream>>>(A);
}

// Round 5
// 699.670 us; speedup vs baseline: 1.5915x; 1.2254x over previous
//
#include <hip/hip_runtime.h>

#define NB 2048
#define HDM 64
#define NLAY 5
#define NBLK 512

// tree-barrier geometry: 64 groups x 8 blocks; 128B (32 u32) per line
#define BAR_U32_PER_SLOT (129*32)   // 64 grp counters + 1 global + 64 flags
#define BAR_SLOTS 24

typedef __bf16 bf16x8 __attribute__((ext_vector_type(8)));
typedef float v4f __attribute__((ext_vector_type(4)));

__device__ __forceinline__ float sigmoidf_(float x){ return 1.f/(1.f+__expf(-x)); }
__device__ __forceinline__ float tanhfast_(float x){
  x = fminf(fmaxf(x, -15.f), 15.f);
  float e = __expf(2.f*x);
  return (e-1.f)/(e+1.f);
}
__device__ __forceinline__ unsigned short f2b_rne(float f){
  unsigned u = __float_as_uint(f);
  unsigned r = u + 0x7FFFu + ((u>>16)&1u);
  return (unsigned short)(r>>16);
}
__device__ __forceinline__ unsigned pk2(float a, float b){
  unsigned ua = (__float_as_uint(a) + 0x8000u) >> 16;
  unsigned ub = (__float_as_uint(b) + 0x8000u) & 0xFFFF0000u;
  return ua | ub;
}

// ---------- device-coherent (sc0 sc1) access helpers ----------
// Cross-block arrays (h0p, Qb, Kb, Vt, o_out, smlp, hsum/bnacc-zeroing) are accessed ONLY
// through these: stores write through to the coherent point, loads bypass L1/L2. No cache
// maintenance is ever needed at grid barriers, and L2 stays warm with weights throughout.

__device__ __forceinline__ float ld_f32_sc(const float* p){
  float v;
  asm volatile("global_load_dword %0, %1, off sc0 sc1\n"
               "s_waitcnt vmcnt(0)"
               : "=v"(v) : "v"(p) : "memory");
  return v;
}
__device__ __forceinline__ void ld4_f32_sc(float& a, float& b, float& c, float& d,
                                           const float* p0, const float* p1,
                                           const float* p2, const float* p3){
  asm volatile("global_load_dword %0, %4, off sc0 sc1\n"
               "global_load_dword %1, %5, off sc0 sc1\n"
               "global_load_dword %2, %6, off sc0 sc1\n"
               "global_load_dword %3, %7, off sc0 sc1\n"
               "s_waitcnt vmcnt(0)"
               : "=&v"(a), "=&v"(b), "=&v"(c), "=&v"(d)
               : "v"(p0), "v"(p1), "v"(p2), "v"(p3) : "memory");
}
__device__ __forceinline__ bf16x8 ld_b16x8_sc_wait(const unsigned short* p){
  bf16x8 v;
  asm volatile("global_load_dwordx4 %0, %1, off sc0 sc1\n"
               "s_waitcnt vmcnt(0)"
               : "=v"(v) : "v"(p) : "memory");
  return v;
}
__device__ __forceinline__ void ld3_b16x8_sc(bf16x8& a, bf16x8& b, bf16x8& c,
                                             const unsigned short* pa,
                                             const unsigned short* pb,
                                             const unsigned short* pc){
  asm volatile("global_load_dwordx4 %0, %3, off sc0 sc1\n"
               "global_load_dwordx4 %1, %4, off sc0 sc1\n"
               "global_load_dwordx4 %2, %5, off sc0 sc1"
               : "=&v"(a), "=&v"(b), "=&v"(c)
               : "v"(pa), "v"(pb), "v"(pc) : "memory");
}
// waitcnt tied to the loaded values ("+v") so the compiler cannot hoist a consumer
// (MFMA reads these regs) above the wait (guide rule #18).
__device__ __forceinline__ void await3(bf16x8& a, bf16x8& b, bf16x8& c){
  asm volatile("s_waitcnt vmcnt(0)" : "+v"(a), "+v"(b), "+v"(c) :: "memory");
  __builtin_amdgcn_sched_barrier(0);
}
__device__ __forceinline__ void st_f32_sc(float* p, float v){
  asm volatile("global_store_dword %0, %1, off sc0 sc1" :: "v"(p), "v"(v) : "memory");
}
__device__ __forceinline__ void st_v4f_sc(float* p, v4f v){
  asm volatile("global_store_dwordx4 %0, %1, off sc0 sc1" :: "v"(p), "v"(v) : "memory");
}
__device__ __forceinline__ void st_u16_sc(unsigned short* p, unsigned short v){
  unsigned vv = v;
  asm volatile("global_store_short %0, %1, off sc0 sc1" :: "v"(p), "v"(vv) : "memory");
}

// ============================ fused kernel ============================
// 512 blocks x 256 threads, __launch_bounds__(256,2): 2 blocks/CU * 256 CU = 512 resident.

struct KArgs {
  const float *x, *tt, *freqs, *fc1W, *fc1b, *fc2W, *fc2b, *nodeW, *nodeb,
              *tprojW, *tprojb, *tcatW, *tcatb, *penb, *pelW, *pelb, *catW, *catb,
              *convWg, *gruWih, *grubih, *gruWhh, *grubhh, *Wqkv, *bqkv, *Wo, *bo,
              *bng, *bnb, *W1, *b1, *W2, *b2, *outW, *outb;
  float *htime, *hbuf, *gh, *s1, *s2, *smlp, *o_out, *hsum, *bnacc, *h0p, *out;
  unsigned short *Qb, *Kb, *Vt;
  unsigned *bar;
};

union SMem {
  struct { float xs[16*260]; float tb0[256]; float tb1[256]; } pre;             // 18688 B
  struct { float sa[256]; float sb[256]; float cvec[64]; } as;                  // 2304 B
  struct { float sa[256]; } a;                                                  // 1024 B
  struct { unsigned short Pl[4*640]; float Os[4*272]; float ms[64]; float ls[64]; } at; // 9984 B
  struct { float sa[256]; float os[256]; float smv[64]; float sgi[192]; float Sb1[256]; float Sb2[256]; } b2; // 5120 B
  struct { float sa[256]; float sh[4*128]; float S2[256]; } c;                  // 4096 B
  struct { float hsT[64*20]; } o;                                               // 5120 B
};

// Two-level tree grid barrier, slot-per-barrier (slots zeroed by the in-graph memset).
// Round-4 post-mortem: single-line arrive+poll = 512-way contention at the coherent
// point ~27us/barrier. Here: 8-way contention on 64 group lines (parallel), one 64-way
// global line, then a flag broadcast to 64 lines polled by only 8 blocks each.
// No cache maintenance: release ordering is structural (each block drains vmcnt before
// arriving; flags set only after ALL arrivals).
__device__ __forceinline__ void gsync(unsigned* base){
  asm volatile("s_waitcnt vmcnt(0)" ::: "memory");   // drain this wave's sc-stores
  __syncthreads();
  if (threadIdx.x == 0){
    const unsigned g = (unsigned)blockIdx.x >> 3;    // 64 groups of 8 blocks
    unsigned* grp   = base + g*32;
    unsigned* glob  = base + 64*32;
    unsigned* flags = base + 65*32;
    unsigned old = __hip_atomic_fetch_add(grp, 1u, __ATOMIC_RELAXED, __HIP_MEMORY_SCOPE_AGENT);
    if (old == 7u){
      unsigned go = __hip_atomic_fetch_add(glob, 1u, __ATOMIC_RELAXED, __HIP_MEMORY_SCOPE_AGENT);
      if (go == 63u){
        #pragma unroll 8
        for (int i=0;i<64;++i)
          __hip_atomic_store(flags + i*32, 1u, __ATOMIC_RELAXED, __HIP_MEMORY_SCOPE_AGENT);
      }
    }
    unsigned spins = 0u;
    while (__hip_atomic_load(flags + g*32, __ATOMIC_RELAXED, __HIP_MEMORY_SCOPE_AGENT) == 0u){
      __builtin_amdgcn_s_sleep(8);
      if (++spins > 1000000u) break;   // fail loud (wrong data), never hang
    }
    asm volatile("" ::: "memory");
  }
  __syncthreads();
}

__global__ __launch_bounds__(256, 2) void k_fused(KArgs A)
{
  __shared__ SMem sm;
  const int t = threadIdx.x;
  const int b = blockIdx.x;
  int slot = 0;

  // ================= Phase P: zero accumulators + time-embedding + GEMM1 =================
  if (b == 0){
    for (int i = t; i < 320 + 1920; i += 256) st_f32_sc(&A.hsum[i], 0.f);  // hsum+bnacc
  }
  {
    // time embedding for rows b*4 + r
    const int r = t>>6, c = t&63;
    const int row = b*4 + r;
    const float tv = A.tt[row];
    float te[16];
    #pragma unroll
    for (int j=0;j<8;++j){
      float sv, cv;
      __sincosf(6.28318530717958647692f*tv*A.freqs[j], &sv, &cv);
      te[j]=sv; te[j+8]=cv;
    }
    float a = A.fc1b[c];
    #pragma unroll
    for (int j=0;j<16;++j) a += te[j]*A.fc1W[j*64+c];
    sm.pre.tb0[r*64+c] = a*sigmoidf_(a);
    __syncthreads();
    float b2v = A.fc2b[c];
    #pragma unroll 8
    for (int k=0;k<64;++k) b2v += sm.pre.tb0[r*64+k]*A.fc2W[k*64+c];
    sm.pre.tb1[r*64+c] = b2v;
    __syncthreads();
    float hti = A.tprojb[c];
    #pragma unroll 8
    for (int k=0;k<64;++k) hti += sm.pre.tb1[r*64+k]*A.tprojW[k*64+c];
    A.htime[row*64+c] = hti;               // block-private: plain store
  }
  {
    // GEMM1 partial: rowgroup rg = b>>2 (16 rows), K-quarter kq = b&3 (1024 k)
    const int rg = b>>2, kq = b&3;
    const int rows0 = rg*16, k0 = kq*1024;
    const int col4 = (t&15)*4;
    const int rq4  = ((t>>4)&3)*4;
    const int ksub = (t>>6)*64;

    float4 a0={0,0,0,0}, a1={0,0,0,0}, a2={0,0,0,0}, a3={0,0,0,0};

    for (int ch=0; ch<4; ++ch){
      __syncthreads();
      #pragma unroll
      for (int i=0;i<4;++i){
        int fi = t + 256*i;
        int xr = fi>>6, kk = (fi&63)<<2;
        *(float4*)&sm.pre.xs[xr*260+kk] =
            *(const float4*)&A.x[(size_t)(rows0+xr)*4096 + k0 + ch*256 + kk];
      }
      __syncthreads();
      const float* wp = &A.nodeW[(size_t)(k0 + ch*256 + ksub)*64 + col4];
      const float* xp = &sm.pre.xs[rq4*260 + ksub];
      #pragma unroll 8
      for (int kk=0; kk<64; ++kk){
        float4 w  = *(const float4*)&wp[kk*64];
        float x0 = xp[kk];
        float x1 = xp[260+kk];
        float x2 = xp[520+kk];
        float x3 = xp[780+kk];
        a0.x += x0*w.x; a0.y += x0*w.y; a0.z += x0*w.z; a0.w += x0*w.w;
        a1.x += x1*w.x; a1.y += x1*w.y; a1.z += x1*w.z; a1.w += x1*w.w;
        a2.x += x2*w.x; a2.y += x2*w.y; a2.z += x2*w.z; a2.w += x2*w.w;
        a3.x += x3*w.x; a3.y += x3*w.y; a3.z += x3*w.z; a3.w += x3*w.w;
      }
    }
    __syncthreads();
    {
      const int kqi = t>>6;
      *(float4*)&sm.pre.xs[(kqi*16 + rq4 + 0)*64 + col4] = a0;
      *(float4*)&sm.pre.xs[(kqi*16 + rq4 + 1)*64 + col4] = a1;
      *(float4*)&sm.pre.xs[(kqi*16 + rq4 + 2)*64 + col4] = a2;
      *(float4*)&sm.pre.xs[(kqi*16 + rq4 + 3)*64 + col4] = a3;
    }
    __syncthreads();
    {
      const int row = t>>4, c4 = (t&15)*4;
      float4 s = {0,0,0,0};
      #pragma unroll
      for (int q=0;q<4;++q){
        float4 v = *(const float4*)&sm.pre.xs[(q*16+row)*64 + c4];
        s.x+=v.x; s.y+=v.y; s.z+=v.z; s.w+=v.w;
      }
      v4f sv = {s.x, s.y, s.z, s.w};
      st_v4f_sc(&A.h0p[(size_t)kq*(NB*HDM) + (rows0+row)*64 + c4], sv);  // cross-block
    }
  }
  gsync(A.bar + (slot++)*BAR_U32_PER_SLOT);   // GEMM1 partials + zeroing at coherent point

  // ================= Phase assemble: rows b*4 + r =================
  {
    const int r = t>>6, c = t&63;
    const int row = b*4 + r;
    if (r==0){
      float pl[16];
      #pragma unroll
      for (int j=0;j<16;++j){
        float a = A.pelb[j];
        for (int w=0;w<20;++w) a += A.penb[w]*A.pelW[w*16+j];
        pl[j]=a;
      }
      float a = A.catb[c];
      #pragma unroll
      for (int j=0;j<16;++j) a += pl[j]*A.catW[(64+j)*64+c];
      sm.as.cvec[c]=a;
    }
    float p0,p1,p2,p3;
    ld4_f32_sc(p0,p1,p2,p3,
               &A.h0p[0*(NB*HDM) + row*64 + c], &A.h0p[1*(NB*HDM) + row*64 + c],
               &A.h0p[2*(NB*HDM) + row*64 + c], &A.h0p[3*(NB*HDM) + row*64 + c]);
    sm.as.sa[t] = A.nodeb[c] + ((p0+p1)+(p2+p3));
    sm.as.sb[t] = A.htime[row*64+c];       // block-private
    __syncthreads();
    float a = A.tcatb[c];
    #pragma unroll 4
    for (int k=0;k<64;++k){
      a += sm.as.sa[r*64+k]*A.tcatW[k*64+c];
      a += sm.as.sb[r*64+k]*A.tcatW[(64+k)*64+c];
    }
    __syncthreads();
    sm.as.sa[t] = a;
    __syncthreads();
    float hv = sm.as.cvec[c];
    #pragma unroll 8
    for (int k=0;k<64;++k) hv += sm.as.sa[r*64+k]*A.catW[k*64+c];
    A.hbuf[row*64+c] = hv;                 // block-private
  }
  // no grid sync: layer-0 phase A reads only this block's own rows of hbuf

  // ================= layers =================
  for (int l=0; l<NLAY; ++l){
    const float* bnaccPrev = (l==0) ? A.bnacc : A.bnacc + (l-1)*384;
    const float* gPrev = (l==0) ? A.bng : A.bng + (l-1)*192 + 128;
    const float* bPrev = (l==0) ? A.bnb : A.bnb + (l-1)*192 + 128;
    const float* Whh = A.gruWhh + l*12288;
    const float* bhh = A.grubhh + l*192;
    const float* Wq  = A.Wqkv + l*12288;
    const float* bqv = A.bqkv + l*192;
    float* hsumL  = A.hsum + l*64;
    float* bnaccL = A.bnacc + l*384;

    // ---- Phase A: [bn3 prev] + hsum + gh + bf16 QKV packs (4 rows) ----
    __syncthreads();   // protect LDS union reuse
    {
      const int row0 = b*4;
      const int rl = t>>6, c = t&63;
      const int row = row0 + rl;
      float hv;
      if (l==0){
        hv = A.hbuf[row*64+c];             // block-private
      } else {
        float mu = bnaccPrev[256+c]*(1.f/NB);          // first-touch lines: plain ok
        float va = bnaccPrev[320+c]*(1.f/NB) - mu*mu;
        float sv = ld_f32_sc(&A.smlp[row*64+c]);       // written via sc: sc read
        hv = gPrev[c]*(sv-mu)*rsqrtf(va+1e-5f)+bPrev[c];
        A.hbuf[row*64+c] = hv;             // block-private
      }
      sm.a.sa[t] = hv;
      __syncthreads();
      if (t<64){
        float s = sm.a.sa[t]+sm.a.sa[64+t]+sm.a.sa[128+t]+sm.a.sa[192+t];
        atomicAdd(&hsumL[t], s);           // device-scope atomic: coherent point
      }
      if (t < 192){
        const int cc = t;
        float ag[4], aq[4];
        float bh = bhh[cc], bq_ = bqv[cc];
        #pragma unroll
        for (int rl2=0;rl2<4;++rl2){ ag[rl2]=bh; aq[rl2]=bq_; }
        #pragma unroll 4
        for (int k=0;k<64;++k){
          float wh = Whh[k*192+cc];
          float wq = Wq [k*192+cc];
          #pragma unroll
          for (int rl2=0;rl2<4;++rl2){
            float hk = sm.a.sa[rl2*64+k];
            ag[rl2] += hk*wh;
            aq[rl2] += hk*wq;
          }
        }
        #pragma unroll
        for (int rl2=0;rl2<4;++rl2){
          int rw = row0 + rl2;
          A.gh[(size_t)rw*192+cc] = ag[rl2];           // block-private
          float aqv = aq[rl2];
          if (cc < 64){
            int hd = cc>>4, dh = cc&15;
            size_t base = ((size_t)(hd<<11) + rw)*32;
            st_u16_sc(&A.Qb[base+dh], f2b_rne(aqv*0.25f));
            st_u16_sc(&A.Qb[base+16+dh], (unsigned short)0);
          } else if (cc < 128){
            int c2 = cc-64, hd = c2>>4, dh = c2&15;
            size_t base = ((size_t)(hd<<11) + rw)*32;
            st_u16_sc(&A.Kb[base+dh], f2b_rne(aqv));
            st_u16_sc(&A.Kb[base+16+dh], (unsigned short)0);
          } else {
            int c2 = cc-128, hd = c2>>4, dh = c2&15;
            st_u16_sc(&A.Vt[((size_t)(hd*16+dh))*2048 + rw], f2b_rne(aqv));
          }
        }
      }
    }
    gsync(A.bar + (slot++)*BAR_U32_PER_SLOT);   // QKV at coherent point

    // ---- Phase attn: unit b = (qt = b&127, head = b>>7), 4 waves x 512 keys ----
    {
      const int w = t>>6, lane = t&63;
      const int q15 = lane & 15, quad = lane >> 4;
      const int qt = b & 127, head = b>>7;
      const int qrow = qt*16 + q15;
      const int key00 = w*512;
      unsigned short* Plw = &sm.at.Pl[w*640];

      const bf16x8 qf = ld_b16x8_sc_wait(&A.Qb[(((size_t)(head<<11))+qrow)*32 + quad*8]);
      const unsigned short* Kb_h = A.Kb + ((size_t)(head<<11))*32;
      const unsigned short* Vrow = A.Vt + ((size_t)(head*16+q15))*2048;

      v4f O = {0.f,0.f,0.f,0.f};
      float m = -1e30f, lsum = 0.f;

      bf16x8 kf0, kf1, vf;
      ld3_b16x8_sc(kf0, kf1, vf,
                   &Kb_h[(size_t)(key00 + q15)*32 + quad*8],
                   &Kb_h[(size_t)(key00 + 16 + q15)*32 + quad*8],
                   &Vrow[key00 + quad*8]);
      await3(kf0, kf1, vf);

      for (int c=0; c<16; ++c){
        bf16x8 nk0, nk1, nv;
        if (c < 15){
          int nk = key00 + (c+1)*32;
          ld3_b16x8_sc(nk0, nk1, nv,
                       &Kb_h[(size_t)(nk + q15)*32 + quad*8],
                       &Kb_h[(size_t)(nk + 16 + q15)*32 + quad*8],
                       &Vrow[nk + quad*8]);
        }
        v4f z = {0.f,0.f,0.f,0.f};
        v4f s0 = __builtin_amdgcn_mfma_f32_16x16x32_bf16(kf0, qf, z, 0,0,0);
        v4f s1 = __builtin_amdgcn_mfma_f32_16x16x32_bf16(kf1, qf, z, 0,0,0);
        float cmax = fmaxf(fmaxf(fmaxf(s0[0],s0[1]),fmaxf(s0[2],s0[3])),
                           fmaxf(fmaxf(s1[0],s1[1]),fmaxf(s1[2],s1[3])));
        cmax = fmaxf(cmax, __shfl_xor(cmax,16,64));
        cmax = fmaxf(cmax, __shfl_xor(cmax,32,64));
        float mnew = fmaxf(m, cmax);
        float alpha = __expf(m - mnew);
        float p0=__expf(s0[0]-mnew), p1=__expf(s0[1]-mnew), p2=__expf(s0[2]-mnew), p3=__expf(s0[3]-mnew);
        float p4=__expf(s1[0]-mnew), p5=__expf(s1[1]-mnew), p6=__expf(s1[2]-mnew), p7=__expf(s1[3]-mnew);
        lsum = alpha*lsum + ((p0+p1)+(p2+p3)+((p4+p5)+(p6+p7)));
        m = mnew;
        O[0]*=alpha; O[1]*=alpha; O[2]*=alpha; O[3]*=alpha;
        *(uint2*)&Plw[q15*40 + quad*4]      = make_uint2(pk2(p0,p1), pk2(p2,p3));
        *(uint2*)&Plw[q15*40 + 16 + quad*4] = make_uint2(pk2(p4,p5), pk2(p6,p7));
        asm volatile("s_waitcnt lgkmcnt(0)" ::: "memory");
        bf16x8 pf = *(const bf16x8*)&Plw[q15*40 + quad*8];
        O = __builtin_amdgcn_mfma_f32_16x16x32_bf16(vf, pf, O, 0,0,0);
        if (c < 15){
          kf0 = nk0; kf1 = nk1; vf = nv;
          await3(kf0, kf1, vf);
        }
      }
      lsum += __shfl_xor(lsum,16,64);
      lsum += __shfl_xor(lsum,32,64);
      #pragma unroll
      for (int j=0;j<4;++j) sm.at.Os[w*272 + q15*17 + quad*4 + j] = O[j];
      if (quad==0){ sm.at.ms[w*16+q15]=m; sm.at.ls[w*16+q15]=lsum; }
      __syncthreads();
      {
        const int dh = t&15, q = t>>4;
        float m0=sm.at.ms[q], m1=sm.at.ms[16+q], m2=sm.at.ms[32+q], m3=sm.at.ms[48+q];
        float mm = fmaxf(fmaxf(m0,m1),fmaxf(m2,m3));
        float a0=__expf(m0-mm), a1=__expf(m1-mm), a2=__expf(m2-mm), a3=__expf(m3-mm);
        float ll = a0*sm.at.ls[q]+a1*sm.at.ls[16+q]+a2*sm.at.ls[32+q]+a3*sm.at.ls[48+q];
        float oo = a0*sm.at.Os[q*17+dh] + a1*sm.at.Os[272+q*17+dh]
                 + a2*sm.at.Os[544+q*17+dh] + a3*sm.at.Os[816+q*17+dh];
        st_f32_sc(&A.o_out[(size_t)(qt*16+q)*64 + head*16 + dh], oo / ll);  // cross-block
      }
    }
    gsync(A.bar + (slot++)*BAR_U32_PER_SLOT);   // o_out at coherent point

    // ---- Phase B2: o-proj + GRU + bn1/bn2 stats (4 rows) ----
    {
      const float* Wg  = A.convWg + l*4096;
      const float* Wih = A.gruWih + l*12288;
      const float* bih = A.grubih + l*192;
      const float* WoL = A.Wo + l*4096;
      const float* boL = A.bo + l*64;
      const int row0 = b*4;

      if (t<64){
        float a=0.f;
        #pragma unroll 8
        for (int k=0;k<64;++k) a += hsumL[k]*Wg[k*64+t];   // hsum: atomics at coherent point
        sm.b2.smv[t]=a;
      }
      {
        const int rl = t>>6, c = t&63;
        sm.b2.sa[t] = A.hbuf[(size_t)(row0+rl)*64+c];                 // block-private
        sm.b2.os[t] = ld_f32_sc(&A.o_out[(size_t)(row0+rl)*64+c]);    // cross-block
      }
      __syncthreads();
      if (t<192){
        float a = bih[t];
        #pragma unroll 8
        for (int k=0;k<64;++k) a += sm.b2.smv[k]*Wih[k*192+t];
        sm.b2.sgi[t]=a;
      }
      __syncthreads();

      {
        const int c = t&63, rg = t>>6;   // one row per thread
        float o2 = boL[c];
        #pragma unroll 4
        for (int k=0;k<64;++k) o2 += sm.b2.os[rg*64+k]*WoL[k*64+c];
        const int row = row0 + rg;
        float hv = sm.b2.sa[rg*64+c];
        float s2v = o2 + hv;
        float ir = sm.b2.sgi[c]      + A.gh[(size_t)row*192+c];
        float iz = sm.b2.sgi[64+c]   + A.gh[(size_t)row*192+64+c];
        float inn = sm.b2.sgi[128+c];
        float hn  = A.gh[(size_t)row*192+128+c];
        float rr_ = sigmoidf_(ir);
        float zz  = sigmoidf_(iz);
        float nn  = tanhfast_(inn + rr_*hn);
        float s1v = (1.f-zz)*nn + zz*hv + hv;   // hc + h
        A.s1[(size_t)row*64+c] = s1v;           // block-private
        A.s2[(size_t)row*64+c] = s2v;           // block-private
        sm.b2.Sb1[rg*64+c] = s1v;
        sm.b2.Sb2[rg*64+c] = s2v;
      }
      __syncthreads();
      if (t<64){
        float a=0.f,aq=0.f,bb=0.f,bq2=0.f;
        #pragma unroll
        for (int rl=0;rl<4;++rl){
          float v1 = sm.b2.Sb1[rl*64+t], v2 = sm.b2.Sb2[rl*64+t];
          a+=v1; aq+=v1*v1; bb+=v2; bq2+=v2*v2;
        }
        atomicAdd(&bnaccL[t],a);     atomicAdd(&bnaccL[64+t],aq);
        atomicAdd(&bnaccL[128+t],bb); atomicAdd(&bnaccL[192+t],bq2);
      }
    }
    gsync(A.bar + (slot++)*BAR_U32_PER_SLOT);   // bn1/bn2 stats complete

    // ---- Phase C: bn1/bn2 apply + MLP + bn3 stats (4 rows) ----
    {
      const float* bngL = A.bng + l*192;
      const float* bnbL = A.bnb + l*192;
      const float* W1l = A.W1 + l*8192;
      const float* b1l = A.b1 + l*128;
      const float* W2l = A.W2 + l*8192;
      const float* b2l = A.b2 + l*64;
      const int row0 = b*4;

      {
        const int rl = t>>6, c = t&63;
        const int row = row0 + rl;
        float mu1 = bnaccL[c]*(1.f/NB);            // first-touch lines: plain ok
        float va1 = bnaccL[64+c]*(1.f/NB) - mu1*mu1;
        float mu2 = bnaccL[128+c]*(1.f/NB);
        float va2 = bnaccL[192+c]*(1.f/NB) - mu2*mu2;
        float h1 = bngL[c]*(A.s1[(size_t)row*64+c]-mu1)*rsqrtf(va1+1e-5f)+bnbL[c];
        float h2 = bngL[64+c]*(A.s2[(size_t)row*64+c]-mu2)*rsqrtf(va2+1e-5f)+bnbL[64+c];
        sm.c.sa[t] = h1+h2;
      }
      __syncthreads();
      {
        const int hj = t&127, rgq = t>>7;   // 2 rows per thread
        float a0v=b1l[hj], a1v=b1l[hj];
        #pragma unroll 4
        for (int k=0;k<64;++k){
          float w = W1l[k*128+hj];
          a0v += sm.c.sa[(rgq*2  )*64+k]*w;
          a1v += sm.c.sa[(rgq*2+1)*64+k]*w;
        }
        sm.c.sh[(rgq*2  )*128+hj] = fmaxf(a0v,0.f);
        sm.c.sh[(rgq*2+1)*128+hj] = fmaxf(a1v,0.f);
      }
      __syncthreads();
      {
        const int c = t&63, rg = t>>6;   // one row per thread
        float mo = b2l[c];
        #pragma unroll 4
        for (int k=0;k<128;++k) mo += sm.c.sh[rg*128+k]*W2l[k*64+c];
        float smv2 = sm.c.sa[rg*64+c] + mo;
        st_f32_sc(&A.smlp[(size_t)(row0+rg)*64+c], smv2);   // cross-block (GEMM2) + self
        sm.c.S2[rg*64+c] = smv2;
      }
      __syncthreads();
      if (t<64){
        float a=0.f,aq=0.f;
        #pragma unroll
        for (int rl=0;rl<4;++rl){ float v=sm.c.S2[rl*64+t]; a+=v; aq+=v*v; }
        atomicAdd(&bnaccL[256+t],a); atomicAdd(&bnaccL[320+t],aq);
      }
    }
    gsync(A.bar + (slot++)*BAR_U32_PER_SLOT);   // bn3 stats + smlp at coherent point
  }

  // ================= Phase out: GEMM2 + fused final bn3 =================
  {
    const float* bnacc4 = A.bnacc + 4*384;
    const float* g4 = A.bng + 896;
    const float* b4 = A.bnb + 896;
    const int rg = b>>2, cg = b&3;
    const int rows0 = rg*16;
    {
      float s0,s1v,s2v,s3;
      const int i0=t, i1=t+256, i2=t+512, i3=t+768;
      ld4_f32_sc(s0,s1v,s2v,s3,
                 &A.smlp[(size_t)(rows0+(i0>>6))*64+(i0&63)],
                 &A.smlp[(size_t)(rows0+(i1>>6))*64+(i1&63)],
                 &A.smlp[(size_t)(rows0+(i2>>6))*64+(i2&63)],
                 &A.smlp[(size_t)(rows0+(i3>>6))*64+(i3&63)]);
      float sv[4] = {s0,s1v,s2v,s3};
      #pragma unroll
      for (int i=0;i<4;++i){
        int idx = t + 256*i;
        int k = idx&63, rr = idx>>6;
        float mu = bnacc4[256+k]*(1.f/NB);
        float va = bnacc4[320+k]*(1.f/NB)-mu*mu;
        sm.o.hsT[k*20+rr] = g4[k]*(sv[i]-mu)*rsqrtf(va+1e-5f)+b4[k];
      }
    }
    __syncthreads();
    const int cc = cg*1024 + t*4;
    float4 acc[16];
    {
      float4 bv = *(const float4*)&A.outb[cc];
      #pragma unroll
      for (int rr=0;rr<16;++rr) acc[rr]=bv;
    }
    #pragma unroll 4
    for (int k=0;k<64;++k){
      float4 w = *(const float4*)&A.outW[(size_t)k*4096+cc];
      const float4* hp = (const float4*)&sm.o.hsT[k*20];
      float4 h0=hp[0], h1=hp[1], h2=hp[2], h3=hp[3];
      acc[0].x+=h0.x*w.x;  acc[0].y+=h0.x*w.y;  acc[0].z+=h0.x*w.z;  acc[0].w+=h0.x*w.w;
      acc[1].x+=h0.y*w.x;  acc[1].y+=h0.y*w.y;  acc[1].z+=h0.y*w.z;  acc[1].w+=h0.y*w.w;
      acc[2].x+=h0.z*w.x;  acc[2].y+=h0.z*w.y;  acc[2].z+=h0.z*w.z;  acc[2].w+=h0.z*w.w;
      acc[3].x+=h0.w*w.x;  acc[3].y+=h0.w*w.y;  acc[3].z+=h0.w*w.z;  acc[3].w+=h0.w*w.w;
      acc[4].x+=h1.x*w.x;  acc[4].y+=h1.x*w.y;  acc[4].z+=h1.x*w.z;  acc[4].w+=h1.x*w.w;
      acc[5].x+=h1.y*w.x;  acc[5].y+=h1.y*w.y;  acc[5].z+=h1.y*w.z;  acc[5].w+=h1.y*w.w;
      acc[6].x+=h1.z*w.x;  acc[6].y+=h1.z*w.y;  acc[6].z+=h1.z*w.z;  acc[6].w+=h1.z*w.w;
      acc[7].x+=h1.w*w.x;  acc[7].y+=h1.w*w.y;  acc[7].z+=h1.w*w.z;  acc[7].w+=h1.w*w.w;
      acc[8].x+=h2.x*w.x;  acc[8].y+=h2.x*w.y;  acc[8].z+=h2.x*w.z;  acc[8].w+=h2.x*w.w;
      acc[9].x+=h2.y*w.x;  acc[9].y+=h2.y*w.y;  acc[9].z+=h2.y*w.z;  acc[9].w+=h2.y*w.w;
      acc[10].x+=h2.z*w.x; acc[10].y+=h2.z*w.y; acc[10].z+=h2.z*w.z; acc[10].w+=h2.z*w.w;
      acc[11].x+=h2.w*w.x; acc[11].y+=h2.w*w.y; acc[11].z+=h2.w*w.z; acc[11].w+=h2.w*w.w;
      acc[12].x+=h3.x*w.x; acc[12].y+=h3.x*w.y; acc[12].z+=h3.x*w.z; acc[12].w+=h3.x*w.w;
      acc[13].x+=h3.y*w.x; acc[13].y+=h3.y*w.y; acc[13].z+=h3.y*w.z; acc[13].w+=h3.y*w.w;
      acc[14].x+=h3.z*w.x; acc[14].y+=h3.z*w.y; acc[14].z+=h3.z*w.z; acc[14].w+=h3.z*w.w;
      acc[15].x+=h3.w*w.x; acc[15].y+=h3.w*w.y; acc[15].z+=h3.w*w.z; acc[15].w+=h3.w*w.w;
    }
    #pragma unroll
    for (int rr=0;rr<16;++rr)
      *(float4*)&A.out[(size_t)(rows0+rr)*4096+cc] = acc[rr];   // kernel-end release flushes
  }
}

// ============================ host ============================

extern "C" void kernel_launch(void* const* d_in, const int* in_sizes, int n_in,
                              void* d_out, int out_size, void* d_ws, size_t ws_size,
                              hipStream_t stream)
{
  (void)in_sizes; (void)n_in; (void)out_size; (void)ws_size;
  KArgs A;
  A.x      = (const float*)d_in[0];
  A.tt     = (const float*)d_in[1];
  A.freqs  = (const float*)d_in[2];
  A.fc1W   = (const float*)d_in[3];
  A.fc1b   = (const float*)d_in[4];
  A.fc2W   = (const float*)d_in[5];
  A.fc2b   = (const float*)d_in[6];
  A.nodeW  = (const float*)d_in[7];
  A.nodeb  = (const float*)d_in[8];
  A.tprojW = (const float*)d_in[9];
  A.tprojb = (const float*)d_in[10];
  A.tcatW  = (const float*)d_in[11];
  A.tcatb  = (const float*)d_in[12];
  A.penb   = (const float*)d_in[14];
  A.pelW   = (const float*)d_in[15];
  A.pelb   = (const float*)d_in[16];
  A.catW   = (const float*)d_in[17];
  A.catb   = (const float*)d_in[18];
  A.convWg = (const float*)d_in[19];
  A.gruWih = (const float*)d_in[20];
  A.grubih = (const float*)d_in[21];
  A.gruWhh = (const float*)d_in[22];
  A.grubhh = (const float*)d_in[23];
  A.Wqkv   = (const float*)d_in[24];
  A.bqkv   = (const float*)d_in[25];
  A.Wo     = (const float*)d_in[26];
  A.bo     = (const float*)d_in[27];
  A.bng    = (const float*)d_in[28];
  A.bnb    = (const float*)d_in[29];
  A.W1     = (const float*)d_in[30];
  A.b1     = (const float*)d_in[31];
  A.W2     = (const float*)d_in[32];
  A.b2     = (const float*)d_in[33];
  A.outW   = (const float*)d_in[34];
  A.outb   = (const float*)d_in[35];

  float* ws = (float*)d_ws;
  A.htime = ws;                      // 131072
  A.hbuf  = A.htime + 131072;        // 131072
  A.gh    = A.hbuf + 131072;         // 393216
  A.s1    = A.gh + 393216;           // 131072
  A.s2    = A.s1 + 131072;           // 131072
  A.smlp  = A.s2 + 131072;           // 131072
  A.o_out = A.smlp + 131072;         // 131072
  A.hsum  = A.o_out + 131072;        // 320
  A.bnacc = A.hsum + 320;            // 1920
  A.Qb = (unsigned short*)(A.bnacc + 1920);   // 262144 ushort
  A.Kb = A.Qb + 262144;                       // 262144 ushort
  A.Vt = A.Kb + 262144;                       // 65536 ushort
  A.h0p  = (float*)(A.Vt + 65536);   // fused path uses slots 0..3 (4*131072)
  A.bar  = (unsigned*)(A.h0p + 4*(NB*HDM));   // tree-barrier region, inside proven ws
  A.out  = (float*)d_out;

  hipMemsetAsync(A.bar, 0, BAR_SLOTS*BAR_U32_PER_SLOT*sizeof(unsigned), stream);
  k_fused<<<dim3(NBLK), dim3(256), 0, stream>>>(A);
}

// Round 6
// 557.324 us; speedup vs baseline: 1.9980x; 1.2554x over previous
//
#include <hip/hip_runtime.h>

#define NB 2048
#define HDM 64
#define NLAY 5
#define NBLK 1024

// barrier region (u32): 128 group lines + 1 global line + 128 flag lines, 32 u32 each
#define BAR_U32 (257*32)
// replicated accumulators
#define HSUMR_F  (8*NLAY*64)     // 2560
#define BNACCR_F (8*NLAY*384)    // 15360

typedef __bf16 bf16x8 __attribute__((ext_vector_type(8)));
typedef float v4f __attribute__((ext_vector_type(4)));

__device__ __forceinline__ float sigmoidf_(float x){ return 1.f/(1.f+__expf(-x)); }
__device__ __forceinline__ float tanhfast_(float x){
  x = fminf(fmaxf(x, -15.f), 15.f);
  float e = __expf(2.f*x);
  return (e-1.f)/(e+1.f);
}
__device__ __forceinline__ unsigned short f2b_rne(float f){
  unsigned u = __float_as_uint(f);
  unsigned r = u + 0x7FFFu + ((u>>16)&1u);
  return (unsigned short)(r>>16);
}
__device__ __forceinline__ unsigned pk2(float a, float b){
  unsigned ua = (__float_as_uint(a) + 0x8000u) >> 16;
  unsigned ub = (__float_as_uint(b) + 0x8000u) & 0xFFFF0000u;
  return ua | ub;
}

// ---------- device-coherent (sc0 sc1) access helpers ----------
__device__ __forceinline__ float ld_f32_sc(const float* p){
  float v;
  asm volatile("global_load_dword %0, %1, off sc0 sc1\n"
               "s_waitcnt vmcnt(0)"
               : "=v"(v) : "v"(p) : "memory");
  return v;
}
__device__ __forceinline__ void ld4_f32_sc(float& a, float& b, float& c, float& d,
                                           const float* p0, const float* p1,
                                           const float* p2, const float* p3){
  asm volatile("global_load_dword %0, %4, off sc0 sc1\n"
               "global_load_dword %1, %5, off sc0 sc1\n"
               "global_load_dword %2, %6, off sc0 sc1\n"
               "global_load_dword %3, %7, off sc0 sc1\n"
               "s_waitcnt vmcnt(0)"
               : "=&v"(a), "=&v"(b), "=&v"(c), "=&v"(d)
               : "v"(p0), "v"(p1), "v"(p2), "v"(p3) : "memory");
}
__device__ __forceinline__ bf16x8 ld_b16x8_sc_wait(const unsigned short* p){
  bf16x8 v;
  asm volatile("global_load_dwordx4 %0, %1, off sc0 sc1\n"
               "s_waitcnt vmcnt(0)"
               : "=v"(v) : "v"(p) : "memory");
  return v;
}
__device__ __forceinline__ void ld3_b16x8_sc(bf16x8& a, bf16x8& b, bf16x8& c,
                                             const unsigned short* pa,
                                             const unsigned short* pb,
                                             const unsigned short* pc){
  asm volatile("global_load_dwordx4 %0, %3, off sc0 sc1\n"
               "global_load_dwordx4 %1, %4, off sc0 sc1\n"
               "global_load_dwordx4 %2, %5, off sc0 sc1"
               : "=&v"(a), "=&v"(b), "=&v"(c)
               : "v"(pa), "v"(pb), "v"(pc) : "memory");
}
__device__ __forceinline__ void await3(bf16x8& a, bf16x8& b, bf16x8& c){
  asm volatile("s_waitcnt vmcnt(0)" : "+v"(a), "+v"(b), "+v"(c) :: "memory");
  __builtin_amdgcn_sched_barrier(0);
}
__device__ __forceinline__ void st_f32_sc(float* p, float v){
  asm volatile("global_store_dword %0, %1, off sc0 sc1" :: "v"(p), "v"(v) : "memory");
}
__device__ __forceinline__ void st_v4f_sc(float* p, v4f v){
  asm volatile("global_store_dwordx4 %0, %1, off sc0 sc1" :: "v"(p), "v"(v) : "memory");
}
__device__ __forceinline__ void st_u16_sc(unsigned short* p, unsigned short v){
  unsigned vv = v;
  asm volatile("global_store_short %0, %1, off sc0 sc1" :: "v"(p), "v"(vv) : "memory");
}

// ============================ fused kernel ============================
// 1024 blocks x 256 threads, __launch_bounds__(256,4): VGPR<=128 + LDS ~19.2KB*4=77KB
// -> 4 blocks/CU * 256 CU = 1024 resident blocks (2x the waves/SIMD of round 5,
// doubling latency hiding). Watchdog in gsync turns any residency surprise into a
// loud numerical failure instead of a hang.

struct KArgs {
  const float *x, *tt, *freqs, *fc1W, *fc1b, *fc2W, *fc2b, *nodeW, *nodeb,
              *tprojW, *tprojb, *tcatW, *tcatb, *penb, *pelW, *pelb, *catW, *catb,
              *convWg, *gruWih, *grubih, *gruWhh, *grubhh, *Wqkv, *bqkv, *Wo, *bo,
              *bng, *bnb, *W1, *b1, *W2, *b2, *outW, *outb;
  float *htime, *hbuf, *s1, *s2, *smlp, *o_out, *h0p, *out;
  float *hsumR, *bnaccR;          // 8-replica accumulators (atomic contention /8)
  unsigned short *Qb, *Kb, *Vt;
  unsigned *bar;
};

union SMem {
  struct { float xs[16*260]; float tb0[128]; float tb1[128]; } pre;              // 17664 B
  struct { float sa[128]; float sb[128]; float cvec[64]; } as;                   // 1280 B
  struct { float sa[128]; float tot3[128]; } a;                                  // 1024 B
  struct { unsigned short Pl[4*640]; float Os[4*272]; float ms[64]; float ls[64]; } at; // 9984 B
  struct { float sa[128]; float os[128]; float smv[64]; float smT[64]; float sgi[192];
           float Sb1[128]; float Sb2[128]; } b2;                                 // 3328 B
  struct { float sa[128]; float totC[256]; float sh[2*128]; float S2[128]; } c;  // 3072 B
  struct { float hsT[64*12]; float totO[128]; } o;                               // 3584 B
};

// Monotonic two-level tree barrier, SINGLE slot (round-number flags; no resets).
// Arrive: 8-way contention on 128 group lines (parallel); group-last bumps one
// 128-way global line; global-last broadcasts round+1 to 128 flag lines, each
// polled by only 8 blocks. No cache maintenance anywhere: all cross-block data
// moves via sc0sc1 (coherent point); release ordering is structural (vmcnt drain
// before arrive; flags only after all arrivals).
__device__ __forceinline__ void gsync(unsigned* base, unsigned round){
  asm volatile("s_waitcnt vmcnt(0)" ::: "memory");   // drain this wave's sc-stores
  __syncthreads();
  if (threadIdx.x == 0){
    const unsigned g = (unsigned)blockIdx.x >> 3;    // 128 groups of 8
    unsigned* grp   = base + g*32;
    unsigned* glob  = base + 128*32;
    unsigned* flags = base + 129*32;
    unsigned old = __hip_atomic_fetch_add(grp, 1u, __ATOMIC_RELAXED, __HIP_MEMORY_SCOPE_AGENT);
    if ((old & 7u) == 7u){                           // 8th arrival of this round
      unsigned go = __hip_atomic_fetch_add(glob, 1u, __ATOMIC_RELAXED, __HIP_MEMORY_SCOPE_AGENT);
      if ((go & 127u) == 127u){                      // 128th group-last of this round
        #pragma unroll 8
        for (int i=0;i<128;++i)
          __hip_atomic_store(flags + i*32, round+1u, __ATOMIC_RELAXED, __HIP_MEMORY_SCOPE_AGENT);
      }
    }
    unsigned spins = 0u;
    while (__hip_atomic_load(flags + g*32, __ATOMIC_RELAXED, __HIP_MEMORY_SCOPE_AGENT) < round+1u){
      __builtin_amdgcn_s_sleep(8);
      if (++spins > 1000000u) break;   // fail loud (wrong data), never hang
    }
    asm volatile("" ::: "memory");
  }
  __syncthreads();
}

__global__ __launch_bounds__(256, 4) void k_fused(KArgs A)
{
  __shared__ SMem sm;
  __shared__ float ghp[2*192];   // block-private GRU gh (A -> B2), persists across attn
  const int t = threadIdx.x;
  const int b = blockIdx.x;
  unsigned rnd = 0;

  // ================= Phase P: time-embedding + GEMM1 (legacy 1024-block cut) =============
  {
    const int r = t>>6, c = t&63;
    if (r < 2){
      const int row = b*2 + r;
      const float tv = A.tt[row];
      float te[16];
      #pragma unroll
      for (int j=0;j<8;++j){
        float sv, cv;
        __sincosf(6.28318530717958647692f*tv*A.freqs[j], &sv, &cv);
        te[j]=sv; te[j+8]=cv;
      }
      float a = A.fc1b[c];
      #pragma unroll
      for (int j=0;j<16;++j) a += te[j]*A.fc1W[j*64+c];
      sm.pre.tb0[r*64+c] = a*sigmoidf_(a);
    }
    __syncthreads();
    if (r < 2){
      float b2v = A.fc2b[c];
      #pragma unroll 8
      for (int k=0;k<64;++k) b2v += sm.pre.tb0[r*64+k]*A.fc2W[k*64+c];
      sm.pre.tb1[r*64+c] = b2v;
    }
    __syncthreads();
    if (r < 2){
      const int row = b*2 + r;
      float hti = A.tprojb[c];
      #pragma unroll 8
      for (int k=0;k<64;++k) hti += sm.pre.tb1[r*64+k]*A.tprojW[k*64+c];
      A.htime[row*64+c] = hti;             // block-private
    }
  }
  {
    // GEMM1 partial: rg = b>>3 (16 rows), kq = b&7 (512 k), 2 chunks of 256
    const int rg = b>>3, kq = b&7;
    const int rows0 = rg*16, k0 = kq*512;
    const int col4 = (t&15)*4;
    const int rq4  = ((t>>4)&3)*4;
    const int ksub = (t>>6)*64;

    float4 a0={0,0,0,0}, a1={0,0,0,0}, a2={0,0,0,0}, a3={0,0,0,0};

    for (int ch=0; ch<2; ++ch){
      __syncthreads();
      #pragma unroll
      for (int i=0;i<4;++i){
        int fi = t + 256*i;
        int xr = fi>>6, kk = (fi&63)<<2;
        *(float4*)&sm.pre.xs[xr*260+kk] =
            *(const float4*)&A.x[(size_t)(rows0+xr)*4096 + k0 + ch*256 + kk];
      }
      __syncthreads();
      const float* wp = &A.nodeW[(size_t)(k0 + ch*256 + ksub)*64 + col4];
      const float* xp = &sm.pre.xs[rq4*260 + ksub];
      #pragma unroll 8
      for (int kk=0; kk<64; ++kk){
        float4 w  = *(const float4*)&wp[kk*64];
        float x0 = xp[kk];
        float x1 = xp[260+kk];
        float x2 = xp[520+kk];
        float x3 = xp[780+kk];
        a0.x += x0*w.x; a0.y += x0*w.y; a0.z += x0*w.z; a0.w += x0*w.w;
        a1.x += x1*w.x; a1.y += x1*w.y; a1.z += x1*w.z; a1.w += x1*w.w;
        a2.x += x2*w.x; a2.y += x2*w.y; a2.z += x2*w.z; a2.w += x2*w.w;
        a3.x += x3*w.x; a3.y += x3*w.y; a3.z += x3*w.z; a3.w += x3*w.w;
      }
    }
    __syncthreads();
    {
      const int kqi = t>>6;
      *(float4*)&sm.pre.xs[(kqi*16 + rq4 + 0)*64 + col4] = a0;
      *(float4*)&sm.pre.xs[(kqi*16 + rq4 + 1)*64 + col4] = a1;
      *(float4*)&sm.pre.xs[(kqi*16 + rq4 + 2)*64 + col4] = a2;
      *(float4*)&sm.pre.xs[(kqi*16 + rq4 + 3)*64 + col4] = a3;
    }
    __syncthreads();
    {
      const int row = t>>4, c4 = (t&15)*4;
      float4 s = {0,0,0,0};
      #pragma unroll
      for (int q=0;q<4;++q){
        float4 v = *(const float4*)&sm.pre.xs[(q*16+row)*64 + c4];
        s.x+=v.x; s.y+=v.y; s.z+=v.z; s.w+=v.w;
      }
      v4f sv = {s.x, s.y, s.z, s.w};
      st_v4f_sc(&A.h0p[(size_t)kq*(NB*HDM) + (rows0+row)*64 + c4], sv);  // cross-block
    }
  }
  gsync(A.bar, rnd++);   // all GEMM1 partials at coherent point

  // ================= Phase assemble: rows b*2 + r (r<2) =================
  {
    const int r = t>>6, c = t&63;
    const int row = b*2 + r;
    if (r==0){
      float pl[16];
      #pragma unroll
      for (int j=0;j<16;++j){
        float a = A.pelb[j];
        for (int w=0;w<20;++w) a += A.penb[w]*A.pelW[w*16+j];
        pl[j]=a;
      }
      float a = A.catb[c];
      #pragma unroll
      for (int j=0;j<16;++j) a += pl[j]*A.catW[(64+j)*64+c];
      sm.as.cvec[c]=a;
    }
    if (r < 2){
      float p0,p1,p2,p3,p4,p5,p6,p7;
      ld4_f32_sc(p0,p1,p2,p3,
                 &A.h0p[(size_t)0*(NB*HDM) + row*64 + c], &A.h0p[(size_t)1*(NB*HDM) + row*64 + c],
                 &A.h0p[(size_t)2*(NB*HDM) + row*64 + c], &A.h0p[(size_t)3*(NB*HDM) + row*64 + c]);
      ld4_f32_sc(p4,p5,p6,p7,
                 &A.h0p[(size_t)4*(NB*HDM) + row*64 + c], &A.h0p[(size_t)5*(NB*HDM) + row*64 + c],
                 &A.h0p[(size_t)6*(NB*HDM) + row*64 + c], &A.h0p[(size_t)7*(NB*HDM) + row*64 + c]);
      sm.as.sa[t] = A.nodeb[c] + (((p0+p1)+(p2+p3)) + ((p4+p5)+(p6+p7)));
      sm.as.sb[t] = A.htime[row*64+c];
    }
    __syncthreads();
    float a = 0.f;
    if (r < 2){
      a = A.tcatb[c];
      #pragma unroll 4
      for (int k=0;k<64;++k){
        a += sm.as.sa[r*64+k]*A.tcatW[k*64+c];
        a += sm.as.sb[r*64+k]*A.tcatW[(64+k)*64+c];
      }
    }
    __syncthreads();
    if (r < 2) sm.as.sa[t] = a;
    __syncthreads();
    if (r < 2){
      float hv = sm.as.cvec[c];
      #pragma unroll 8
      for (int k=0;k<64;++k) hv += sm.as.sa[r*64+k]*A.catW[k*64+c];
      A.hbuf[row*64+c] = hv;               // block-private
    }
  }
  // no grid sync: layer-0 phase A reads only this block's own rows of hbuf

  // ================= layers =================
  for (int l=0; l<NLAY; ++l){
    const float* gPrev = (l==0) ? A.bng : A.bng + (l-1)*192 + 128;
    const float* bPrev = (l==0) ? A.bnb : A.bnb + (l-1)*192 + 128;
    const float* Whh = A.gruWhh + l*12288;
    const float* bhh = A.grubhh + l*192;
    const float* Wq  = A.Wqkv + l*12288;
    const float* bqv = A.bqkv + l*192;
    const int rep = b & 7;

    // ---- Phase A: [bn3 prev] + hsum + gh(LDS) + bf16 QKV packs (2 rows) ----
    __syncthreads();   // protect LDS union reuse vs preceding phase
    {
      const int row0 = b*2;
      if (l>0 && t<128){
        float s = 0.f;
        #pragma unroll
        for (int rp=0;rp<8;++rp) s += A.bnaccR[rp*1920 + (l-1)*384 + 256 + t];
        sm.a.tot3[t] = s;
      }
      __syncthreads();
      if (t < 128){
        const int rl = t>>6, c = t&63;
        const int row = row0 + rl;
        float hv;
        if (l==0){
          hv = A.hbuf[row*64+c];           // block-private
        } else {
          float mu = sm.a.tot3[c]*(1.f/NB);
          float va = sm.a.tot3[64+c]*(1.f/NB) - mu*mu;
          float sv = ld_f32_sc(&A.smlp[row*64+c]);
          hv = gPrev[c]*(sv-mu)*rsqrtf(va+1e-5f)+bPrev[c];
          A.hbuf[row*64+c] = hv;           // block-private
        }
        sm.a.sa[t] = hv;
      }
      __syncthreads();
      if (t<64){
        float s = sm.a.sa[t] + sm.a.sa[64+t];
        atomicAdd(&A.hsumR[rep*320 + l*64 + t], s);
      }
      if (t < 192){
        const int cc = t;
        float ag[2], aq[2];
        float bh = bhh[cc], bq_ = bqv[cc];
        ag[0]=bh; ag[1]=bh; aq[0]=bq_; aq[1]=bq_;
        #pragma unroll 4
        for (int k=0;k<64;++k){
          float wh = Whh[k*192+cc];
          float wq = Wq [k*192+cc];
          float h0 = sm.a.sa[k], h1 = sm.a.sa[64+k];
          ag[0] += h0*wh; ag[1] += h1*wh;
          aq[0] += h0*wq; aq[1] += h1*wq;
        }
        ghp[cc]     = ag[0];
        ghp[192+cc] = ag[1];
        #pragma unroll
        for (int rl2=0;rl2<2;++rl2){
          int rw = row0 + rl2;
          float aqv = aq[rl2];
          if (cc < 64){
            int hd = cc>>4, dh = cc&15;
            size_t base = ((size_t)(hd<<11) + rw)*32;
            st_u16_sc(&A.Qb[base+dh], f2b_rne(aqv*0.25f));
            st_u16_sc(&A.Qb[base+16+dh], (unsigned short)0);
          } else if (cc < 128){
            int c2 = cc-64, hd = c2>>4, dh = c2&15;
            size_t base = ((size_t)(hd<<11) + rw)*32;
            st_u16_sc(&A.Kb[base+dh], f2b_rne(aqv));
            st_u16_sc(&A.Kb[base+16+dh], (unsigned short)0);
          } else {
            int c2 = cc-128, hd = c2>>4, dh = c2&15;
            st_u16_sc(&A.Vt[((size_t)(hd*16+dh))*2048 + rw], f2b_rne(aqv));
          }
        }
      }
    }
    gsync(A.bar, rnd++);   // QKV at coherent point

    // ---- Phase attn: 512 units on blocks b<512 (qt = b&127, head = b>>7) ----
    if (b < 512){
      const int w = t>>6, lane = t&63;
      const int q15 = lane & 15, quad = lane >> 4;
      const int qt = b & 127, head = b>>7;
      const int qrow = qt*16 + q15;
      const int key00 = w*512;
      unsigned short* Plw = &sm.at.Pl[w*640];

      const bf16x8 qf = ld_b16x8_sc_wait(&A.Qb[(((size_t)(head<<11))+qrow)*32 + quad*8]);
      const unsigned short* Kb_h = A.Kb + ((size_t)(head<<11))*32;
      const unsigned short* Vrow = A.Vt + ((size_t)(head*16+q15))*2048;

      v4f O = {0.f,0.f,0.f,0.f};
      float m = -1e30f, lsum = 0.f;

      bf16x8 kf0, kf1, vf;
      ld3_b16x8_sc(kf0, kf1, vf,
                   &Kb_h[(size_t)(key00 + q15)*32 + quad*8],
                   &Kb_h[(size_t)(key00 + 16 + q15)*32 + quad*8],
                   &Vrow[key00 + quad*8]);
      await3(kf0, kf1, vf);

      for (int c=0; c<16; ++c){
        bf16x8 nk0, nk1, nv;
        if (c < 15){
          int nk = key00 + (c+1)*32;
          ld3_b16x8_sc(nk0, nk1, nv,
                       &Kb_h[(size_t)(nk + q15)*32 + quad*8],
                       &Kb_h[(size_t)(nk + 16 + q15)*32 + quad*8],
                       &Vrow[nk + quad*8]);
        }
        v4f z = {0.f,0.f,0.f,0.f};
        v4f s0 = __builtin_amdgcn_mfma_f32_16x16x32_bf16(kf0, qf, z, 0,0,0);
        v4f s1 = __builtin_amdgcn_mfma_f32_16x16x32_bf16(kf1, qf, z, 0,0,0);
        float cmax = fmaxf(fmaxf(fmaxf(s0[0],s0[1]),fmaxf(s0[2],s0[3])),
                           fmaxf(fmaxf(s1[0],s1[1]),fmaxf(s1[2],s1[3])));
        cmax = fmaxf(cmax, __shfl_xor(cmax,16,64));
        cmax = fmaxf(cmax, __shfl_xor(cmax,32,64));
        float mnew = fmaxf(m, cmax);
        float alpha = __expf(m - mnew);
        float p0=__expf(s0[0]-mnew), p1=__expf(s0[1]-mnew), p2=__expf(s0[2]-mnew), p3=__expf(s0[3]-mnew);
        float p4=__expf(s1[0]-mnew), p5=__expf(s1[1]-mnew), p6=__expf(s1[2]-mnew), p7=__expf(s1[3]-mnew);
        lsum = alpha*lsum + ((p0+p1)+(p2+p3)+((p4+p5)+(p6+p7)));
        m = mnew;
        O[0]*=alpha; O[1]*=alpha; O[2]*=alpha; O[3]*=alpha;
        *(uint2*)&Plw[q15*40 + quad*4]      = make_uint2(pk2(p0,p1), pk2(p2,p3));
        *(uint2*)&Plw[q15*40 + 16 + quad*4] = make_uint2(pk2(p4,p5), pk2(p6,p7));
        asm volatile("s_waitcnt lgkmcnt(0)" ::: "memory");
        bf16x8 pf = *(const bf16x8*)&Plw[q15*40 + quad*8];
        O = __builtin_amdgcn_mfma_f32_16x16x32_bf16(vf, pf, O, 0,0,0);
        if (c < 15){
          kf0 = nk0; kf1 = nk1; vf = nv;
          await3(kf0, kf1, vf);
        }
      }
      lsum += __shfl_xor(lsum,16,64);
      lsum += __shfl_xor(lsum,32,64);
      #pragma unroll
      for (int j=0;j<4;++j) sm.at.Os[w*272 + q15*17 + quad*4 + j] = O[j];
      if (quad==0){ sm.at.ms[w*16+q15]=m; sm.at.ls[w*16+q15]=lsum; }
      __syncthreads();
      {
        const int dh = t&15, q = t>>4;
        float m0=sm.at.ms[q], m1=sm.at.ms[16+q], m2=sm.at.ms[32+q], m3=sm.at.ms[48+q];
        float mm = fmaxf(fmaxf(m0,m1),fmaxf(m2,m3));
        float a0=__expf(m0-mm), a1=__expf(m1-mm), a2=__expf(m2-mm), a3=__expf(m3-mm);
        float ll = a0*sm.at.ls[q]+a1*sm.at.ls[16+q]+a2*sm.at.ls[32+q]+a3*sm.at.ls[48+q];
        float oo = a0*sm.at.Os[q*17+dh] + a1*sm.at.Os[272+q*17+dh]
                 + a2*sm.at.Os[544+q*17+dh] + a3*sm.at.Os[816+q*17+dh];
        st_f32_sc(&A.o_out[(size_t)(qt*16+q)*64 + head*16 + dh], oo / ll);  // cross-block
      }
    }
    gsync(A.bar, rnd++);   // o_out at coherent point

    // ---- Phase B2: o-proj + GRU + bn1/bn2 stats (2 rows) ----
    {
      const float* Wg  = A.convWg + l*4096;
      const float* Wih = A.gruWih + l*12288;
      const float* bih = A.grubih + l*192;
      const float* WoL = A.Wo + l*4096;
      const float* boL = A.bo + l*64;
      const int row0 = b*2;

      if (t<64){
        float s = 0.f;
        #pragma unroll
        for (int rp=0;rp<8;++rp) s += A.hsumR[rp*320 + l*64 + t];
        sm.b2.smT[t] = s;
      }
      if (t<128){
        const int rl = t>>6, c = t&63;
        sm.b2.sa[t] = A.hbuf[(size_t)(row0+rl)*64+c];                 // block-private
        sm.b2.os[t] = ld_f32_sc(&A.o_out[(size_t)(row0+rl)*64+c]);    // cross-block
      }
      __syncthreads();
      if (t<64){
        float a=0.f;
        #pragma unroll 8
        for (int k=0;k<64;++k) a += sm.b2.smT[k]*Wg[k*64+t];
        sm.b2.smv[t]=a;
      }
      __syncthreads();
      if (t<192){
        float a = bih[t];
        #pragma unroll 8
        for (int k=0;k<64;++k) a += sm.b2.smv[k]*Wih[k*192+t];
        sm.b2.sgi[t]=a;
      }
      __syncthreads();
      if (t<128){
        const int c = t&63, rg = t>>6;   // one row per thread
        float o2 = boL[c];
        #pragma unroll 4
        for (int k=0;k<64;++k) o2 += sm.b2.os[rg*64+k]*WoL[k*64+c];
        const int row = row0 + rg;
        float hv = sm.b2.sa[rg*64+c];
        float s2v = o2 + hv;
        float ir = sm.b2.sgi[c]      + ghp[rg*192+c];
        float iz = sm.b2.sgi[64+c]   + ghp[rg*192+64+c];
        float inn = sm.b2.sgi[128+c];
        float hn  = ghp[rg*192+128+c];
        float rr_ = sigmoidf_(ir);
        float zz  = sigmoidf_(iz);
        float nn  = tanhfast_(inn + rr_*hn);
        float s1v = (1.f-zz)*nn + zz*hv + hv;   // hc + h
        A.s1[(size_t)row*64+c] = s1v;           // block-private
        A.s2[(size_t)row*64+c] = s2v;           // block-private
        sm.b2.Sb1[rg*64+c] = s1v;
        sm.b2.Sb2[rg*64+c] = s2v;
      }
      __syncthreads();
      if (t<64){
        float a = sm.b2.Sb1[t] + sm.b2.Sb1[64+t];
        float aq = sm.b2.Sb1[t]*sm.b2.Sb1[t] + sm.b2.Sb1[64+t]*sm.b2.Sb1[64+t];
        float bb = sm.b2.Sb2[t] + sm.b2.Sb2[64+t];
        float bq2 = sm.b2.Sb2[t]*sm.b2.Sb2[t] + sm.b2.Sb2[64+t]*sm.b2.Sb2[64+t];
        float* bl = &A.bnaccR[rep*1920 + l*384];
        atomicAdd(&bl[t],a);      atomicAdd(&bl[64+t],aq);
        atomicAdd(&bl[128+t],bb); atomicAdd(&bl[192+t],bq2);
      }
    }
    gsync(A.bar, rnd++);   // bn1/bn2 stats complete

    // ---- Phase C: bn1/bn2 apply + MLP + bn3 stats (2 rows) ----
    {
      const float* bngL = A.bng + l*192;
      const float* bnbL = A.bnb + l*192;
      const float* W1l = A.W1 + l*8192;
      const float* b1l = A.b1 + l*128;
      const float* W2l = A.W2 + l*8192;
      const float* b2l = A.b2 + l*64;
      const int row0 = b*2;

      {
        float s = 0.f;
        #pragma unroll
        for (int rp=0;rp<8;++rp) s += A.bnaccR[rp*1920 + l*384 + t&255 ? 0 : 0]; // placeholder
        (void)s;
      }
      {
        float s = 0.f;
        #pragma unroll
        for (int rp=0;rp<8;++rp) s += A.bnaccR[rp*1920 + l*384 + t];
        sm.c.totC[t] = s;     // t in [0,256): bn1/bn2 sums+sqs totals
      }
      __syncthreads();
      if (t<128){
        const int rl = t>>6, c = t&63;
        const int row = row0 + rl;
        float mu1 = sm.c.totC[c]*(1.f/NB);
        float va1 = sm.c.totC[64+c]*(1.f/NB) - mu1*mu1;
        float mu2 = sm.c.totC[128+c]*(1.f/NB);
        float va2 = sm.c.totC[192+c]*(1.f/NB) - mu2*mu2;
        float h1 = bngL[c]*(A.s1[(size_t)row*64+c]-mu1)*rsqrtf(va1+1e-5f)+bnbL[c];
        float h2 = bngL[64+c]*(A.s2[(size_t)row*64+c]-mu2)*rsqrtf(va2+1e-5f)+bnbL[64+c];
        sm.c.sa[t] = h1+h2;
      }
      __syncthreads();
      {
        const int hj = t&127, rgq = t>>7;   // one row per thread
        float a0v=b1l[hj];
        #pragma unroll 4
        for (int k=0;k<64;++k) a0v += sm.c.sa[rgq*64+k]*W1l[k*128+hj];
        sm.c.sh[rgq*128+hj] = fmaxf(a0v,0.f);
      }
      __syncthreads();
      if (t<128){
        const int c = t&63, rg = t>>6;   // one row per thread
        float mo = b2l[c];
        #pragma unroll 4
        for (int k=0;k<128;++k) mo += sm.c.sh[rg*128+k]*W2l[k*64+c];
        float smv2 = sm.c.sa[rg*64+c] + mo;
        st_f32_sc(&A.smlp[(size_t)(row0+rg)*64+c], smv2);   // cross-block (GEMM2) + self
        sm.c.S2[rg*64+c] = smv2;
      }
      __syncthreads();
      if (t<64){
        float v0 = sm.c.S2[t], v1 = sm.c.S2[64+t];
        float* bl = &A.bnaccR[rep*1920 + l*384];
        atomicAdd(&bl[256+t], v0+v1);
        atomicAdd(&bl[320+t], v0*v0+v1*v1);
      }
    }
    gsync(A.bar, rnd++);   // bn3 stats + smlp at coherent point
  }

  // ================= Phase out: GEMM2 + fused final bn3 (8 rows x 1024 cols) =============
  {
    const float* g4 = A.bng + 896;
    const float* b4 = A.bnb + 896;
    const int rg = b>>2, cg = b&3;
    const int rows0 = rg*8;
    if (t<128){
      float s = 0.f;
      #pragma unroll
      for (int rp=0;rp<8;++rp) s += A.bnaccR[rp*1920 + 4*384 + 256 + t];
      sm.o.totO[t] = s;
    }
    __syncthreads();
    #pragma unroll
    for (int i=0;i<2;++i){
      int idx = t + 256*i;
      int k = idx&63, rr = idx>>6;    // rr in 0..7
      float sv = ld_f32_sc(&A.smlp[(size_t)(rows0+rr)*64+k]);
      float mu = sm.o.totO[k]*(1.f/NB);
      float va = sm.o.totO[64+k]*(1.f/NB)-mu*mu;
      sm.o.hsT[k*12+rr] = g4[k]*(sv-mu)*rsqrtf(va+1e-5f)+b4[k];
    }
    __syncthreads();
    const int cc = cg*1024 + t*4;
    float4 acc[8];
    {
      float4 bv = *(const float4*)&A.outb[cc];
      #pragma unroll
      for (int rr=0;rr<8;++rr) acc[rr]=bv;
    }
    #pragma unroll 4
    for (int k=0;k<64;++k){
      float4 w = *(const float4*)&A.outW[(size_t)k*4096+cc];
      const float4* hp = (const float4*)&sm.o.hsT[k*12];
      float4 h0=hp[0], h1=hp[1];
      acc[0].x+=h0.x*w.x;  acc[0].y+=h0.x*w.y;  acc[0].z+=h0.x*w.z;  acc[0].w+=h0.x*w.w;
      acc[1].x+=h0.y*w.x;  acc[1].y+=h0.y*w.y;  acc[1].z+=h0.y*w.z;  acc[1].w+=h0.y*w.w;
      acc[2].x+=h0.z*w.x;  acc[2].y+=h0.z*w.y;  acc[2].z+=h0.z*w.z;  acc[2].w+=h0.z*w.w;
      acc[3].x+=h0.w*w.x;  acc[3].y+=h0.w*w.y;  acc[3].z+=h0.w*w.z;  acc[3].w+=h0.w*w.w;
      acc[4].x+=h1.x*w.x;  acc[4].y+=h1.x*w.y;  acc[4].z+=h1.x*w.z;  acc[4].w+=h1.x*w.w;
      acc[5].x+=h1.y*w.x;  acc[5].y+=h1.y*w.y;  acc[5].z+=h1.y*w.z;  acc[5].w+=h1.y*w.w;
      acc[6].x+=h1.z*w.x;  acc[6].y+=h1.z*w.y;  acc[6].z+=h1.z*w.z;  acc[6].w+=h1.z*w.w;
      acc[7].x+=h1.w*w.x;  acc[7].y+=h1.w*w.y;  acc[7].z+=h1.w*w.z;  acc[7].w+=h1.w*w.w;
    }
    #pragma unroll
    for (int rr=0;rr<8;++rr)
      *(float4*)&A.out[(size_t)(rows0+rr)*4096+cc] = acc[rr];   // kernel-end release flushes
  }
}

// ============================ host ============================

extern "C" void kernel_launch(void* const* d_in, const int* in_sizes, int n_in,
                              void* d_out, int out_size, void* d_ws, size_t ws_size,
                              hipStream_t stream)
{
  (void)in_sizes; (void)n_in; (void)out_size; (void)ws_size;
  KArgs A;
  A.x      = (const float*)d_in[0];
  A.tt     = (const float*)d_in[1];
  A.freqs  = (const float*)d_in[2];
  A.fc1W   = (const float*)d_in[3];
  A.fc1b   = (const float*)d_in[4];
  A.fc2W   = (const float*)d_in[5];
  A.fc2b   = (const float*)d_in[6];
  A.nodeW  = (const float*)d_in[7];
  A.nodeb  = (const float*)d_in[8];
  A.tprojW = (const float*)d_in[9];
  A.tprojb = (const float*)d_in[10];
  A.tcatW  = (const float*)d_in[11];
  A.tcatb  = (const float*)d_in[12];
  A.penb   = (const float*)d_in[14];
  A.pelW   = (const float*)d_in[15];
  A.pelb   = (const float*)d_in[16];
  A.catW   = (const float*)d_in[17];
  A.catb   = (const float*)d_in[18];
  A.convWg = (const float*)d_in[19];
  A.gruWih = (const float*)d_in[20];
  A.grubih = (const float*)d_in[21];
  A.gruWhh = (const float*)d_in[22];
  A.grubhh = (const float*)d_in[23];
  A.Wqkv   = (const float*)d_in[24];
  A.bqkv   = (const float*)d_in[25];
  A.Wo     = (const float*)d_in[26];
  A.bo     = (const float*)d_in[27];
  A.bng    = (const float*)d_in[28];
  A.bnb    = (const float*)d_in[29];
  A.W1     = (const float*)d_in[30];
  A.b1     = (const float*)d_in[31];
  A.W2     = (const float*)d_in[32];
  A.b2     = (const float*)d_in[33];
  A.outW   = (const float*)d_in[34];
  A.outb   = (const float*)d_in[35];

  // Workspace layout identical to the proven round-0 footprint; the old `gh` region
  // (393216 floats, freed by moving gh to LDS) now hosts barrier + replicas.
  float* ws = (float*)d_ws;
  A.htime = ws;                            // 131072
  A.hbuf  = A.htime + 131072;              // 131072
  float* ghRegion = A.hbuf + 131072;       // 393216 (repurposed)
  A.s1    = ghRegion + 393216;             // 131072
  A.s2    = A.s1 + 131072;                 // 131072
  A.smlp  = A.s2 + 131072;                 // 131072
  A.o_out = A.smlp + 131072;               // 131072
  float* hsum_legacy = A.o_out + 131072;   // 320 (unused)
  float* bnacc_legacy = hsum_legacy + 320; // 1920 (unused)
  A.Qb = (unsigned short*)(bnacc_legacy + 1920);   // 262144 ushort
  A.Kb = A.Qb + 262144;                            // 262144 ushort
  A.Vt = A.Kb + 262144;                            // 65536 ushort
  A.h0p  = (float*)(A.Vt + 65536);         // 8*131072 (all 8 slices used again)
  A.out  = (float*)d_out;

  A.bar    = (unsigned*)ghRegion;                 // 8224 u32
  A.hsumR  = ghRegion + BAR_U32;                  // 2560 f
  A.bnaccR = A.hsumR + HSUMR_F;                   // 15360 f

  hipMemsetAsync(A.bar, 0, (BAR_U32 + HSUMR_F + BNACCR_F)*sizeof(unsigned), stream);
  k_fused<<<dim3(NBLK), dim3(256), 0, stream>>>(A);
}

// Round 9
// 544.567 us; speedup vs baseline: 2.0448x; 1.0234x over previous
//
#include <hip/hip_runtime.h>

#define NB 2048
#define HDM 64
#define NLAY 5
#define NBLK 1024
#define REP 16

// barrier region (u32): 128 group lines + 1 global line + 128 flag lines, 32 u32 each
#define BAR_U32 (257*32)                 // 8224
#define HSUMR_F  (REP*NLAY*64)           // 5120
#define BNACCR_F (REP*NLAY*384)          // 30720

typedef __bf16 bf16x8 __attribute__((ext_vector_type(8)));
typedef float v4f __attribute__((ext_vector_type(4)));

__device__ __forceinline__ float sigmoidf_(float x){ return 1.f/(1.f+__expf(-x)); }
__device__ __forceinline__ float tanhfast_(float x){
  x = fminf(fmaxf(x, -15.f), 15.f);
  float e = __expf(2.f*x);
  return (e-1.f)/(e+1.f);
}
__device__ __forceinline__ unsigned short f2b_rne(float f){
  unsigned u = __float_as_uint(f);
  unsigned r = u + 0x7FFFu + ((u>>16)&1u);
  return (unsigned short)(r>>16);
}
__device__ __forceinline__ unsigned pk2(float a, float b){
  unsigned ua = (__float_as_uint(a) + 0x8000u) >> 16;
  unsigned ub = (__float_as_uint(b) + 0x8000u) & 0xFFFF0000u;
  return ua | ub;
}

// ---------- device-coherent (sc0 sc1) access helpers ----------
// Multi-rewrite cross-block arrays (h0p, o_out, smlp, QKV writes) go through these
// (write through to the coherent point / bypass the non-coherent caches on read).
// QKV READS in attention are plain cached loads: first in-launch touch of sc-written
// data (round-6 empirically validated across 5 layers) -> L2 reuse across the 128
// q-tiles per head. Round 8's manual depth-2 vmcnt pipeline is REVERTED (it copied
// register groups before their waits -- undefined data -> NaN); the compiler's own
// next-tile prefetch on plain loads is correct and sufficient.

__device__ __forceinline__ float ld_f32_sc(const float* p){
  float v;
  asm volatile("global_load_dword %0, %1, off sc0 sc1\n"
               "s_waitcnt vmcnt(0)"
               : "=v"(v) : "v"(p) : "memory");
  return v;
}
__device__ __forceinline__ void ld4_f32_sc(float& a, float& b, float& c, float& d,
                                           const float* p0, const float* p1,
                                           const float* p2, const float* p3){
  asm volatile("global_load_dword %0, %4, off sc0 sc1\n"
               "global_load_dword %1, %5, off sc0 sc1\n"
               "global_load_dword %2, %6, off sc0 sc1\n"
               "global_load_dword %3, %7, off sc0 sc1\n"
               "s_waitcnt vmcnt(0)"
               : "=&v"(a), "=&v"(b), "=&v"(c), "=&v"(d)
               : "v"(p0), "v"(p1), "v"(p2), "v"(p3) : "memory");
}
__device__ __forceinline__ void st_f32_sc(float* p, float v){
  asm volatile("global_store_dword %0, %1, off sc0 sc1" :: "v"(p), "v"(v) : "memory");
}
__device__ __forceinline__ void st_v4f_sc(float* p, v4f v){
  asm volatile("global_store_dwordx4 %0, %1, off sc0 sc1" :: "v"(p), "v"(v) : "memory");
}
__device__ __forceinline__ void st_u16_sc(unsigned short* p, unsigned short v){
  unsigned vv = v;
  asm volatile("global_store_short %0, %1, off sc0 sc1" :: "v"(p), "v"(vv) : "memory");
}

// ============================ fused kernel ============================
// 1024 blocks x 256 threads, __launch_bounds__(256,4): 4 blocks/CU * 256 CU = 1024
// resident. gsync watchdog turns any surprise into fast wrong data, never a hang.

struct KArgs {
  const float *x, *tt, *freqs, *fc1W, *fc1b, *fc2W, *fc2b, *nodeW, *nodeb,
              *tprojW, *tprojb, *tcatW, *tcatb, *penb, *pelW, *pelb, *catW, *catb,
              *convWg, *gruWih, *grubih, *gruWhh, *grubhh, *Wqkv, *bqkv, *Wo, *bo,
              *bng, *bnb, *W1, *b1, *W2, *b2, *outW, *outb;
  float *htime, *hbuf, *s1, *s2, *smlp, *o_out, *h0p, *out;
  float *hsumR, *bnaccR;          // REP-replica accumulators (atomic contention /REP)
  unsigned short *Qb, *Kb, *Vt;   // Vt full 131072 ushorts, no h0p overlap
  unsigned *bar;
};

union SMem {
  struct { float xs[16*260]; float tb0[128]; float tb1[128]; } pre;              // 17664 B
  struct { float sa[128]; float sb[128]; float cvec[64]; } as;                   // 1280 B
  struct { float sa[128]; float tot3[128]; } a;                                  // 1024 B
  struct { unsigned short Pl[4*640]; float Os[4*272]; float ms[64]; float ls[64]; } at; // 9984 B
  struct { float sa[128]; float os[128]; float smv[64]; float smT[64]; float sgi[192];
           float Sb1[128]; float Sb2[128]; } b2;                                 // 3328 B
  struct { float sa[128]; float totC[256]; float sh[2*128]; float S2[128]; } c;  // 3072 B
  struct { float hsT[64*12]; float totO[128]; } o;                               // 3584 B
};

// Monotonic two-level tree grid barrier (single slot, round-number flags, no resets).
// 8-way contention on 128 group lines (parallel) -> one 128-way global line ->
// broadcast round+1 to 128 flag lines polled by 8 blocks each. No cache maintenance:
// release ordering is structural (vmcnt drain before arrive; flags after all arrivals).
__device__ __forceinline__ void gsync(unsigned* base, unsigned round){
  asm volatile("s_waitcnt vmcnt(0)" ::: "memory");   // drain this wave's sc-stores
  __syncthreads();
  if (threadIdx.x == 0){
    const unsigned g = (unsigned)blockIdx.x >> 3;    // 128 groups of 8
    unsigned* grp   = base + g*32;
    unsigned* glob  = base + 128*32;
    unsigned* flags = base + 129*32;
    unsigned old = __hip_atomic_fetch_add(grp, 1u, __ATOMIC_RELAXED, __HIP_MEMORY_SCOPE_AGENT);
    if ((old & 7u) == 7u){
      unsigned go = __hip_atomic_fetch_add(glob, 1u, __ATOMIC_RELAXED, __HIP_MEMORY_SCOPE_AGENT);
      if ((go & 127u) == 127u){
        #pragma unroll 8
        for (int i=0;i<128;++i)
          __hip_atomic_store(flags + i*32, round+1u, __ATOMIC_RELAXED, __HIP_MEMORY_SCOPE_AGENT);
      }
    }
    unsigned spins = 0u;
    while (__hip_atomic_load(flags + g*32, __ATOMIC_RELAXED, __HIP_MEMORY_SCOPE_AGENT) < round+1u){
      __builtin_amdgcn_s_sleep(8);
      if (++spins > 200000u) break;   // fail loud (wrong data) quickly, never time out
    }
    asm volatile("" ::: "memory");
  }
  __syncthreads();
}

__global__ __launch_bounds__(256, 4) void k_fused(KArgs A)
{
  __shared__ SMem sm;
  __shared__ float ghp[2*192];   // block-private GRU gh (A -> B2), persists across attn
  const int t = threadIdx.x;
  const int b = blockIdx.x;
  unsigned rnd = 0;

  // ================= Phase P: time-embedding + GEMM1 (legacy 1024-block cut) =============
  {
    const int r = t>>6, c = t&63;
    if (r < 2){
      const int row = b*2 + r;
      const float tv = A.tt[row];
      float te[16];
      #pragma unroll
      for (int j=0;j<8;++j){
        float sv, cv;
        __sincosf(6.28318530717958647692f*tv*A.freqs[j], &sv, &cv);
        te[j]=sv; te[j+8]=cv;
      }
      float a = A.fc1b[c];
      #pragma unroll
      for (int j=0;j<16;++j) a += te[j]*A.fc1W[j*64+c];
      sm.pre.tb0[r*64+c] = a*sigmoidf_(a);
    }
    __syncthreads();
    if (r < 2){
      float b2v = A.fc2b[c];
      #pragma unroll 8
      for (int k=0;k<64;++k) b2v += sm.pre.tb0[r*64+k]*A.fc2W[k*64+c];
      sm.pre.tb1[r*64+c] = b2v;
    }
    __syncthreads();
    if (r < 2){
      const int row = b*2 + r;
      float hti = A.tprojb[c];
      #pragma unroll 8
      for (int k=0;k<64;++k) hti += sm.pre.tb1[r*64+k]*A.tprojW[k*64+c];
      A.htime[row*64+c] = hti;             // block-private
    }
  }
  {
    // GEMM1 partial: rg = b>>3 (16 rows), kq = b&7 (512 k), 2 chunks of 256
    const int rg = b>>3, kq = b&7;
    const int rows0 = rg*16, k0 = kq*512;
    const int col4 = (t&15)*4;
    const int rq4  = ((t>>4)&3)*4;
    const int ksub = (t>>6)*64;

    float4 a0={0,0,0,0}, a1={0,0,0,0}, a2={0,0,0,0}, a3={0,0,0,0};

    for (int ch=0; ch<2; ++ch){
      __syncthreads();
      #pragma unroll
      for (int i=0;i<4;++i){
        int fi = t + 256*i;
        int xr = fi>>6, kk = (fi&63)<<2;
        *(float4*)&sm.pre.xs[xr*260+kk] =
            *(const float4*)&A.x[(size_t)(rows0+xr)*4096 + k0 + ch*256 + kk];
      }
      __syncthreads();
      const float* wp = &A.nodeW[(size_t)(k0 + ch*256 + ksub)*64 + col4];
      const float* xp = &sm.pre.xs[rq4*260 + ksub];
      #pragma unroll 8
      for (int kk=0; kk<64; ++kk){
        float4 w  = *(const float4*)&wp[kk*64];
        float x0 = xp[kk];
        float x1 = xp[260+kk];
        float x2 = xp[520+kk];
        float x3 = xp[780+kk];
        a0.x += x0*w.x; a0.y += x0*w.y; a0.z += x0*w.z; a0.w += x0*w.w;
        a1.x += x1*w.x; a1.y += x1*w.y; a1.z += x1*w.z; a1.w += x1*w.w;
        a2.x += x2*w.x; a2.y += x2*w.y; a2.z += x2*w.z; a2.w += x2*w.w;
        a3.x += x3*w.x; a3.y += x3*w.y; a3.z += x3*w.z; a3.w += x3*w.w;
      }
    }
    __syncthreads();
    {
      const int kqi = t>>6;
      *(float4*)&sm.pre.xs[(kqi*16 + rq4 + 0)*64 + col4] = a0;
      *(float4*)&sm.pre.xs[(kqi*16 + rq4 + 1)*64 + col4] = a1;
      *(float4*)&sm.pre.xs[(kqi*16 + rq4 + 2)*64 + col4] = a2;
      *(float4*)&sm.pre.xs[(kqi*16 + rq4 + 3)*64 + col4] = a3;
    }
    __syncthreads();
    {
      const int row = t>>4, c4 = (t&15)*4;
      float4 s = {0,0,0,0};
      #pragma unroll
      for (int q=0;q<4;++q){
        float4 v = *(const float4*)&sm.pre.xs[(q*16+row)*64 + c4];
        s.x+=v.x; s.y+=v.y; s.z+=v.z; s.w+=v.w;
      }
      v4f sv = {s.x, s.y, s.z, s.w};
      st_v4f_sc(&A.h0p[(size_t)kq*(NB*HDM) + (rows0+row)*64 + c4], sv);  // cross-block
    }
  }
  gsync(A.bar, rnd++);   // all GEMM1 partials at coherent point

  // ================= Phase assemble: rows b*2 + r (r<2) =================
  {
    const int r = t>>6, c = t&63;
    const int row = b*2 + r;
    if (r==0){
      float pl[16];
      #pragma unroll
      for (int j=0;j<16;++j){
        float a = A.pelb[j];
        for (int w=0;w<20;++w) a += A.penb[w]*A.pelW[w*16+j];
        pl[j]=a;
      }
      float a = A.catb[c];
      #pragma unroll
      for (int j=0;j<16;++j) a += pl[j]*A.catW[(64+j)*64+c];
      sm.as.cvec[c]=a;
    }
    if (r < 2){
      float p0,p1,p2,p3,p4,p5,p6,p7;
      ld4_f32_sc(p0,p1,p2,p3,
                 &A.h0p[(size_t)0*(NB*HDM) + row*64 + c], &A.h0p[(size_t)1*(NB*HDM) + row*64 + c],
                 &A.h0p[(size_t)2*(NB*HDM) + row*64 + c], &A.h0p[(size_t)3*(NB*HDM) + row*64 + c]);
      ld4_f32_sc(p4,p5,p6,p7,
                 &A.h0p[(size_t)4*(NB*HDM) + row*64 + c], &A.h0p[(size_t)5*(NB*HDM) + row*64 + c],
                 &A.h0p[(size_t)6*(NB*HDM) + row*64 + c], &A.h0p[(size_t)7*(NB*HDM) + row*64 + c]);
      sm.as.sa[t] = A.nodeb[c] + (((p0+p1)+(p2+p3)) + ((p4+p5)+(p6+p7)));
      sm.as.sb[t] = A.htime[row*64+c];
    }
    __syncthreads();
    float a = 0.f;
    if (r < 2){
      a = A.tcatb[c];
      #pragma unroll 4
      for (int k=0;k<64;++k){
        a += sm.as.sa[r*64+k]*A.tcatW[k*64+c];
        a += sm.as.sb[r*64+k]*A.tcatW[(64+k)*64+c];
      }
    }
    __syncthreads();
    if (r < 2) sm.as.sa[t] = a;
    __syncthreads();
    if (r < 2){
      float hv = sm.as.cvec[c];
      #pragma unroll 8
      for (int k=0;k<64;++k) hv += sm.as.sa[r*64+k]*A.catW[k*64+c];
      A.hbuf[row*64+c] = hv;               // block-private
    }
  }
  // no grid sync: layer-0 phase A reads only this block's own rows of hbuf
  // (Vt no longer overlaps h0p, so phase-A writes cannot race assemble reads)

  // ================= layers =================
  for (int l=0; l<NLAY; ++l){
    const float* gPrev = (l==0) ? A.bng : A.bng + (l-1)*192 + 128;
    const float* bPrev = (l==0) ? A.bnb : A.bnb + (l-1)*192 + 128;
    const float* Whh = A.gruWhh + l*12288;
    const float* bhh = A.grubhh + l*192;
    const float* Wq  = A.Wqkv + l*12288;
    const float* bqv = A.bqkv + l*192;
    const int rep = b & (REP-1);

    // ---- Phase A: [bn3 prev] + hsum + gh(LDS) + bf16 QKV packs (2 rows) ----
    __syncthreads();   // protect LDS union reuse vs preceding phase
    {
      const int row0 = b*2;
      if (l>0 && t<128){
        float s = 0.f;
        #pragma unroll
        for (int rp=0;rp<REP;++rp) s += A.bnaccR[rp*1920 + (l-1)*384 + 256 + t];
        sm.a.tot3[t] = s;
      }
      __syncthreads();
      if (t < 128){
        const int rl = t>>6, c = t&63;
        const int row = row0 + rl;
        float hv;
        if (l==0){
          hv = A.hbuf[row*64+c];           // block-private
        } else {
          float mu = sm.a.tot3[c]*(1.f/NB);
          float va = sm.a.tot3[64+c]*(1.f/NB) - mu*mu;
          float sv = ld_f32_sc(&A.smlp[row*64+c]);
          hv = gPrev[c]*(sv-mu)*rsqrtf(va+1e-5f)+bPrev[c];
          A.hbuf[row*64+c] = hv;           // block-private
        }
        sm.a.sa[t] = hv;
      }
      __syncthreads();
      if (t<64){
        float s = sm.a.sa[t] + sm.a.sa[64+t];
        atomicAdd(&A.hsumR[rep*320 + l*64 + t], s);
      }
      if (t < 192){
        const int cc = t;
        float ag[2], aq[2];
        float bh = bhh[cc], bq_ = bqv[cc];
        ag[0]=bh; ag[1]=bh; aq[0]=bq_; aq[1]=bq_;
        #pragma unroll 4
        for (int k=0;k<64;++k){
          float wh = Whh[k*192+cc];
          float wq = Wq [k*192+cc];
          float h0 = sm.a.sa[k], h1 = sm.a.sa[64+k];
          ag[0] += h0*wh; ag[1] += h1*wh;
          aq[0] += h0*wq; aq[1] += h1*wq;
        }
        ghp[cc]     = ag[0];
        ghp[192+cc] = ag[1];
        #pragma unroll
        for (int rl2=0;rl2<2;++rl2){
          int rw = row0 + rl2;
          float aqv = aq[rl2];
          if (cc < 64){
            int hd = cc>>4, dh = cc&15;
            size_t base = ((size_t)(hd<<11) + rw)*32;
            st_u16_sc(&A.Qb[base+dh], f2b_rne(aqv*0.25f));
            if (l==0) st_u16_sc(&A.Qb[base+16+dh], (unsigned short)0);  // pad once/launch
          } else if (cc < 128){
            int c2 = cc-64, hd = c2>>4, dh = c2&15;
            size_t base = ((size_t)(hd<<11) + rw)*32;
            st_u16_sc(&A.Kb[base+dh], f2b_rne(aqv));
            if (l==0) st_u16_sc(&A.Kb[base+16+dh], (unsigned short)0);  // pad once/launch
          } else {
            int c2 = cc-128, hd = c2>>4, dh = c2&15;
            st_u16_sc(&A.Vt[((size_t)(hd*16+dh))*2048 + rw], f2b_rne(aqv));
          }
        }
      }
    }
    gsync(A.bar, rnd++);   // QKV at coherent point

    // ---- Phase attn: 512 units on blocks b<512; plain cached Q/K/V reads ----
    // (round-6 validated: first in-launch cached touch of sc-written data; compiler's
    //  next-tile prefetch + auto waitcnts; L2 reuse across the 128 q-tiles per head)
    if (b < 512){
      const int w = t>>6, lane = t&63;
      const int q15 = lane & 15, quad = lane >> 4;
      const int qt = b & 127, head = b>>7;
      const int qrow = qt*16 + q15;
      const int key00 = w*512;
      unsigned short* Plw = &sm.at.Pl[w*640];

      const bf16x8 qf = *(const bf16x8*)&A.Qb[(((size_t)(head<<11))+qrow)*32 + quad*8];
      const unsigned short* Kb_h = A.Kb + ((size_t)(head<<11))*32;
      const unsigned short* Vrow = A.Vt + ((size_t)(head*16+q15))*2048;

      v4f O = {0.f,0.f,0.f,0.f};
      float m = -1e30f, lsum = 0.f;

      bf16x8 kf0 = *(const bf16x8*)&Kb_h[(size_t)(key00 + q15)*32 + quad*8];
      bf16x8 kf1 = *(const bf16x8*)&Kb_h[(size_t)(key00 + 16 + q15)*32 + quad*8];
      bf16x8 vf  = *(const bf16x8*)&Vrow[key00 + quad*8];

      for (int c=0; c<16; ++c){
        bf16x8 nk0, nk1, nv;
        if (c < 15){
          int nk = key00 + (c+1)*32;
          nk0 = *(const bf16x8*)&Kb_h[(size_t)(nk + q15)*32 + quad*8];
          nk1 = *(const bf16x8*)&Kb_h[(size_t)(nk + 16 + q15)*32 + quad*8];
          nv  = *(const bf16x8*)&Vrow[nk + quad*8];
        }
        v4f z = {0.f,0.f,0.f,0.f};
        v4f s0 = __builtin_amdgcn_mfma_f32_16x16x32_bf16(kf0, qf, z, 0,0,0);
        v4f s1 = __builtin_amdgcn_mfma_f32_16x16x32_bf16(kf1, qf, z, 0,0,0);
        float cmax = fmaxf(fmaxf(fmaxf(s0[0],s0[1]),fmaxf(s0[2],s0[3])),
                           fmaxf(fmaxf(s1[0],s1[1]),fmaxf(s1[2],s1[3])));
        cmax = fmaxf(cmax, __shfl_xor(cmax,16,64));
        cmax = fmaxf(cmax, __shfl_xor(cmax,32,64));
        float mnew = fmaxf(m, cmax);
        float alpha = __expf(m - mnew);
        float p0=__expf(s0[0]-mnew), p1=__expf(s0[1]-mnew), p2=__expf(s0[2]-mnew), p3=__expf(s0[3]-mnew);
        float p4=__expf(s1[0]-mnew), p5=__expf(s1[1]-mnew), p6=__expf(s1[2]-mnew), p7=__expf(s1[3]-mnew);
        lsum = alpha*lsum + ((p0+p1)+(p2+p3)+((p4+p5)+(p6+p7)));
        m = mnew;
        O[0]*=alpha; O[1]*=alpha; O[2]*=alpha; O[3]*=alpha;
        *(uint2*)&Plw[q15*40 + quad*4]      = make_uint2(pk2(p0,p1), pk2(p2,p3));
        *(uint2*)&Plw[q15*40 + 16 + quad*4] = make_uint2(pk2(p4,p5), pk2(p6,p7));
        asm volatile("s_waitcnt lgkmcnt(0)" ::: "memory");
        bf16x8 pf = *(const bf16x8*)&Plw[q15*40 + quad*8];
        O = __builtin_amdgcn_mfma_f32_16x16x32_bf16(vf, pf, O, 0,0,0);
        kf0 = nk0; kf1 = nk1; vf = nv;
      }
      lsum += __shfl_xor(lsum,16,64);
      lsum += __shfl_xor(lsum,32,64);
      #pragma unroll
      for (int j=0;j<4;++j) sm.at.Os[w*272 + q15*17 + quad*4 + j] = O[j];
      if (quad==0){ sm.at.ms[w*16+q15]=m; sm.at.ls[w*16+q15]=lsum; }
      __syncthreads();
      {
        const int dh = t&15, q = t>>4;
        float m0=sm.at.ms[q], m1=sm.at.ms[16+q], m2=sm.at.ms[32+q], m3=sm.at.ms[48+q];
        float mm = fmaxf(fmaxf(m0,m1),fmaxf(m2,m3));
        float a0=__expf(m0-mm), a1=__expf(m1-mm), a2=__expf(m2-mm), a3=__expf(m3-mm);
        float ll = a0*sm.at.ls[q]+a1*sm.at.ls[16+q]+a2*sm.at.ls[32+q]+a3*sm.at.ls[48+q];
        float oo = a0*sm.at.Os[q*17+dh] + a1*sm.at.Os[272+q*17+dh]
                 + a2*sm.at.Os[544+q*17+dh] + a3*sm.at.Os[816+q*17+dh];
        st_f32_sc(&A.o_out[(size_t)(qt*16+q)*64 + head*16 + dh], oo / ll);  // cross-block
      }
    }
    gsync(A.bar, rnd++);   // o_out at coherent point

    // ---- Phase B2: o-proj + GRU + bn1/bn2 stats (2 rows) ----
    {
      const float* Wg  = A.convWg + l*4096;
      const float* Wih = A.gruWih + l*12288;
      const float* bih = A.grubih + l*192;
      const float* WoL = A.Wo + l*4096;
      const float* boL = A.bo + l*64;
      const int row0 = b*2;

      if (t<64){
        float s = 0.f;
        #pragma unroll
        for (int rp=0;rp<REP;++rp) s += A.hsumR[rp*320 + l*64 + t];
        sm.b2.smT[t] = s;
      }
      if (t<128){
        const int rl = t>>6, c = t&63;
        sm.b2.sa[t] = A.hbuf[(size_t)(row0+rl)*64+c];                 // block-private
        sm.b2.os[t] = ld_f32_sc(&A.o_out[(size_t)(row0+rl)*64+c]);    // cross-block
      }
      __syncthreads();
      if (t<64){
        float a=0.f;
        #pragma unroll 8
        for (int k=0;k<64;++k) a += sm.b2.smT[k]*Wg[k*64+t];
        sm.b2.smv[t]=a;
      }
      __syncthreads();
      if (t<192){
        float a = bih[t];
        #pragma unroll 8
        for (int k=0;k<64;++k) a += sm.b2.smv[k]*Wih[k*192+t];
        sm.b2.sgi[t]=a;
      }
      __syncthreads();
      if (t<128){
        const int c = t&63, rg = t>>6;   // one row per thread
        float o2 = boL[c];
        #pragma unroll 4
        for (int k=0;k<64;++k) o2 += sm.b2.os[rg*64+k]*WoL[k*64+c];
        const int row = row0 + rg;
        float hv = sm.b2.sa[rg*64+c];
        float s2v = o2 + hv;
        float ir = sm.b2.sgi[c]      + ghp[rg*192+c];
        float iz = sm.b2.sgi[64+c]   + ghp[rg*192+64+c];
        float inn = sm.b2.sgi[128+c];
        float hn  = ghp[rg*192+128+c];
        float rr_ = sigmoidf_(ir);
        float zz  = sigmoidf_(iz);
        float nn  = tanhfast_(inn + rr_*hn);
        float s1v = (1.f-zz)*nn + zz*hv + hv;   // hc + h
        A.s1[(size_t)row*64+c] = s1v;           // block-private
        A.s2[(size_t)row*64+c] = s2v;           // block-private
        sm.b2.Sb1[rg*64+c] = s1v;
        sm.b2.Sb2[rg*64+c] = s2v;
      }
      __syncthreads();
      if (t<64){
        float a = sm.b2.Sb1[t] + sm.b2.Sb1[64+t];
        float aq = sm.b2.Sb1[t]*sm.b2.Sb1[t] + sm.b2.Sb1[64+t]*sm.b2.Sb1[64+t];
        float bb = sm.b2.Sb2[t] + sm.b2.Sb2[64+t];
        float bq2 = sm.b2.Sb2[t]*sm.b2.Sb2[t] + sm.b2.Sb2[64+t]*sm.b2.Sb2[64+t];
        float* bl = &A.bnaccR[rep*1920 + l*384];
        atomicAdd(&bl[t],a);      atomicAdd(&bl[64+t],aq);
        atomicAdd(&bl[128+t],bb); atomicAdd(&bl[192+t],bq2);
      }
    }
    gsync(A.bar, rnd++);   // bn1/bn2 stats complete

    // ---- Phase C: bn1/bn2 apply + MLP + bn3 stats (2 rows) ----
    {
      const float* bngL = A.bng + l*192;
      const float* bnbL = A.bnb + l*192;
      const float* W1l = A.W1 + l*8192;
      const float* b1l = A.b1 + l*128;
      const float* W2l = A.W2 + l*8192;
      const float* b2l = A.b2 + l*64;
      const int row0 = b*2;

      {
        float s = 0.f;
        #pragma unroll
        for (int rp=0;rp<REP;++rp) s += A.bnaccR[rp*1920 + l*384 + t];
        sm.c.totC[t] = s;     // t in [0,256): bn1/bn2 sums+sqs totals
      }
      __syncthreads();
      if (t<128){
        const int rl = t>>6, c = t&63;
        const int row = row0 + rl;
        float mu1 = sm.c.totC[c]*(1.f/NB);
        float va1 = sm.c.totC[64+c]*(1.f/NB) - mu1*mu1;
        float mu2 = sm.c.totC[128+c]*(1.f/NB);
        float va2 = sm.c.totC[192+c]*(1.f/NB) - mu2*mu2;
        float h1 = bngL[c]*(A.s1[(size_t)row*64+c]-mu1)*rsqrtf(va1+1e-5f)+bnbL[c];
        float h2 = bngL[64+c]*(A.s2[(size_t)row*64+c]-mu2)*rsqrtf(va2+1e-5f)+bnbL[64+c];
        sm.c.sa[t] = h1+h2;
      }
      __syncthreads();
      {
        const int hj = t&127, rgq = t>>7;   // one row per thread
        float a0v=b1l[hj];
        #pragma unroll 4
        for (int k=0;k<64;++k) a0v += sm.c.sa[rgq*64+k]*W1l[k*128+hj];
        sm.c.sh[rgq*128+hj] = fmaxf(a0v,0.f);
      }
      __syncthreads();
      if (t<128){
        const int c = t&63, rg = t>>6;   // one row per thread
        float mo = b2l[c];
        #pragma unroll 4
        for (int k=0;k<128;++k) mo += sm.c.sh[rg*128+k]*W2l[k*64+c];
        float smv2 = sm.c.sa[rg*64+c] + mo;
        st_f32_sc(&A.smlp[(size_t)(row0+rg)*64+c], smv2);   // cross-block (GEMM2) + self
        sm.c.S2[rg*64+c] = smv2;
      }
      __syncthreads();
      if (t<64){
        float v0 = sm.c.S2[t], v1 = sm.c.S2[64+t];
        float* bl = &A.bnaccR[rep*1920 + l*384];
        atomicAdd(&bl[256+t], v0+v1);
        atomicAdd(&bl[320+t], v0*v0+v1*v1);
      }
    }
    gsync(A.bar, rnd++);   // bn3 stats + smlp at coherent point
  }

  // ================= Phase out: GEMM2 + fused final bn3 (8 rows x 1024 cols) =============
  {
    const float* g4 = A.bng + 896;
    const float* b4 = A.bnb + 896;
    const int rg = b>>2, cg = b&3;
    const int rows0 = rg*8;
    if (t<128){
      float s = 0.f;
      #pragma unroll
      for (int rp=0;rp<REP;++rp) s += A.bnaccR[rp*1920 + 4*384 + 256 + t];
      sm.o.totO[t] = s;
    }
    __syncthreads();
    #pragma unroll
    for (int i=0;i<2;++i){
      int idx = t + 256*i;
      int k = idx&63, rr = idx>>6;    // rr in 0..7
      float sv = ld_f32_sc(&A.smlp[(size_t)(rows0+rr)*64+k]);
      float mu = sm.o.totO[k]*(1.f/NB);
      float va = sm.o.totO[64+k]*(1.f/NB)-mu*mu;
      sm.o.hsT[k*12+rr] = g4[k]*(sv-mu)*rsqrtf(va+1e-5f)+b4[k];
    }
    __syncthreads();
    const int cc = cg*1024 + t*4;
    float4 acc[8];
    {
      float4 bv = *(const float4*)&A.outb[cc];
      #pragma unroll
      for (int rr=0;rr<8;++rr) acc[rr]=bv;
    }
    #pragma unroll 4
    for (int k=0;k<64;++k){
      float4 w = *(const float4*)&A.outW[(size_t)k*4096+cc];
      const float4* hp = (const float4*)&sm.o.hsT[k*12];
      float4 h0=hp[0], h1=hp[1];
      acc[0].x+=h0.x*w.x;  acc[0].y+=h0.x*w.y;  acc[0].z+=h0.x*w.z;  acc[0].w+=h0.x*w.w;
      acc[1].x+=h0.y*w.x;  acc[1].y+=h0.y*w.y;  acc[1].z+=h0.y*w.z;  acc[1].w+=h0.y*w.w;
      acc[2].x+=h0.z*w.x;  acc[2].y+=h0.z*w.y;  acc[2].z+=h0.z*w.z;  acc[2].w+=h0.z*w.w;
      acc[3].x+=h0.w*w.x;  acc[3].y+=h0.w*w.y;  acc[3].z+=h0.w*w.z;  acc[3].w+=h0.w*w.w;
      acc[4].x+=h1.x*w.x;  acc[4].y+=h1.x*w.y;  acc[4].z+=h1.x*w.z;  acc[4].w+=h1.x*w.w;
      acc[5].x+=h1.y*w.x;  acc[5].y+=h1.y*w.y;  acc[5].z+=h1.y*w.z;  acc[5].w+=h1.y*w.w;
      acc[6].x+=h1.z*w.x;  acc[6].y+=h1.z*w.y;  acc[6].z+=h1.z*w.z;  acc[6].w+=h1.z*w.w;
      acc[7].x+=h1.w*w.x;  acc[7].y+=h1.w*w.y;  acc[7].z+=h1.w*w.z;  acc[7].w+=h1.w*w.w;
    }
    #pragma unroll
    for (int rr=0;rr<8;++rr)
      *(float4*)&A.out[(size_t)(rows0+rr)*4096+cc] = acc[rr];   // kernel-end release flushes
  }
}

// ============================ host ============================

extern "C" void kernel_launch(void* const* d_in, const int* in_sizes, int n_in,
                              void* d_out, int out_size, void* d_ws, size_t ws_size,
                              hipStream_t stream)
{
  (void)in_sizes; (void)n_in; (void)out_size; (void)ws_size;
  KArgs A;
  A.x      = (const float*)d_in[0];
  A.tt     = (const float*)d_in[1];
  A.freqs  = (const float*)d_in[2];
  A.fc1W   = (const float*)d_in[3];
  A.fc1b   = (const float*)d_in[4];
  A.fc2W   = (const float*)d_in[5];
  A.fc2b   = (const float*)d_in[6];
  A.nodeW  = (const float*)d_in[7];
  A.nodeb  = (const float*)d_in[8];
  A.tprojW = (const float*)d_in[9];
  A.tprojb = (const float*)d_in[10];
  A.tcatW  = (const float*)d_in[11];
  A.tcatb  = (const float*)d_in[12];
  A.penb   = (const float*)d_in[14];
  A.pelW   = (const float*)d_in[15];
  A.pelb   = (const float*)d_in[16];
  A.catW   = (const float*)d_in[17];
  A.catb   = (const float*)d_in[18];
  A.convWg = (const float*)d_in[19];
  A.gruWih = (const float*)d_in[20];
  A.grubih = (const float*)d_in[21];
  A.gruWhh = (const float*)d_in[22];
  A.grubhh = (const float*)d_in[23];
  A.Wqkv   = (const float*)d_in[24];
  A.bqkv   = (const float*)d_in[25];
  A.Wo     = (const float*)d_in[26];
  A.bo     = (const float*)d_in[27];
  A.bng    = (const float*)d_in[28];
  A.bnb    = (const float*)d_in[29];
  A.W1     = (const float*)d_in[30];
  A.b1     = (const float*)d_in[31];
  A.W2     = (const float*)d_in[32];
  A.b2     = (const float*)d_in[33];
  A.outW   = (const float*)d_in[34];
  A.outb   = (const float*)d_in[35];

  // Workspace: identical footprint to the proven round-0 layout. The legacy gh region
  // (gh lives in LDS now) hosts barrier + replicas + the FULL-SIZE Vt (131072 ushorts)
  // -- removes the legacy Vt/h0p overlap race. Qb/Kb/h0p keep legacy positions.
  float* ws = (float*)d_ws;
  A.htime = ws;                            // 131072
  A.hbuf  = A.htime + 131072;              // 131072
  float* ghRegion = A.hbuf + 131072;       // 393216 (repurposed)
  A.s1    = ghRegion + 393216;             // 131072
  A.s2    = A.s1 + 131072;                 // 131072
  A.smlp  = A.s2 + 131072;                 // 131072
  A.o_out = A.smlp + 131072;               // 131072
  float* hsum_legacy = A.o_out + 131072;   // 320 (unused)
  float* bnacc_legacy = hsum_legacy + 320; // 1920 (unused)
  A.Qb = (unsigned short*)(bnacc_legacy + 1920);   // 262144 ushort
  A.Kb = A.Qb + 262144;                            // 262144 ushort
  unsigned short* vt_legacy = A.Kb + 262144;       // 65536 ushort (dead padding)
  A.h0p  = (float*)(vt_legacy + 65536);    // 8*131072 floats (used only in P/assemble)
  A.out  = (float*)d_out;

  A.bar    = (unsigned*)ghRegion;                       // 8224 u32
  A.hsumR  = ghRegion + BAR_U32;                        // 5120 f
  A.bnaccR = A.hsumR + HSUMR_F;                         // 30720 f
  A.Vt     = (unsigned short*)(A.bnaccR + BNACCR_F);    // 131072 ushort, no overlap

  hipMemsetAsync(A.bar, 0, (BAR_U32 + HSUMR_F + BNACCR_F)*sizeof(unsigned), stream);
  k_fused<<<dim3(NBLK), dim3(256), 0, stream>>>(A);
}